// Round 7
// baseline (3454.055 us; speedup 1.0000x reference)
//
#include <hip/hip_runtime.h>
#include <hip/hip_bf16.h>

// ---------------------------------------------------------------------------
// Round 13: 4-way COLUMN-SPLIT encoder with L3 quad-exchange.
//   Per-CU weight bytes were the wall (768KB/step); register-ring fixes are
//   dead (allocator refuses, 3 rounds of evidence). Split the 256 u-columns
//   across 4 blocks: 256 blocks = 64 rowgroups x 4 col-quarters, 4 waves.
//   Weight stream drops to 192KB/step/CU through R10's proven DMA ring
//   (strict vmcnt(3) waits -- safe under any foreign-op interleave by
//   in-order retirement). Per-step quad-exchanges via agent-scope atomics:
//     #1 attn partials (16 floats) -- hidden under gate MFMAs
//     #2 h,c after cell: h->mid (its real layout!), c->cx (reuses dead
//        'inputs' region); gather 16KB back into LDS hcb.
//   Flags fA/fH[96][64] zeroed per launch by k_zero; bounded spins.
// ---------------------------------------------------------------------------

typedef unsigned short ushort_t;
using short4v = __attribute__((ext_vector_type(4))) short;   // 4 x bf16
using short8  = __attribute__((ext_vector_type(8))) short;   // 8 x bf16
using floatx4 = __attribute__((ext_vector_type(4))) float;   // MFMA accumulator

#define DEVFN static __device__ __forceinline__

DEVFN float bs2f(ushort_t u) {
    union { float f; unsigned v; } c; c.v = ((unsigned)u) << 16; return c.f;
}
DEVFN ushort_t f2bs(float f) {
    __hip_bfloat16 h = __float2bfloat16(f);
    return *reinterpret_cast<ushort_t*>(&h);
}
DEVFN float gload(const void* p, long i, int bf) {
    if (bf) return bs2f(((const ushort_t*)p)[i]);
    return ((const float*)p)[i];
}
DEVFN float sigm(float x) { return 1.f / (1.f + __expf(-x)); }
DEVFN float ftanh(float x) {
    float t = __expf(-2.f * fabsf(x));
    float r = (1.f - t) / (1.f + t);
    return copysignf(r, x);
}
DEVFN short8 ld8(const ushort_t* p) { return *reinterpret_cast<const short8*>(p); }

// barrier publishing LDS writes only (no vmcnt drain -> DMA refills stay live)
DEVFN void bar_lgkm() {
    asm volatile("s_waitcnt lgkmcnt(0)" ::: "memory");
    __builtin_amdgcn_s_barrier();
}

// async global->LDS DMA: 64 lanes x 16B; per-lane global addr, uniform LDS base
DEVFN void gload_lds16(const ushort_t* g, ushort_t* l) {
    typedef const __attribute__((address_space(1))) unsigned int gu32;
    typedef __attribute__((address_space(3))) unsigned int lu32;
    __builtin_amdgcn_global_load_lds((gu32*)g, (lu32*)l, 16, 0, 0);
}

// strict ring wait: consume slot j only after its refill retired.
// vmcnt(3) is ALWAYS safe: exactly 3 ring refills are newer than slot j's,
// foreign VMEM ops only make the wait stricter (in-order retirement).
#define VW3() asm volatile("s_waitcnt vmcnt(3)" ::: "memory")

DEVFN const ushort_t* chunk_ptr(const ushort_t* wesW, const ushort_t* whhW, int j) {
    // stream order per step: j 0..15 = wes chunks, 16..47 = whh chunks
    return (j < 16) ? (wesW + (j << 9)) : (whhW + ((j - 16) << 9));
}

// agent-scope atomics (coherent at L3 across XCDs)
DEVFN void at_st32(unsigned* p, unsigned v) {
    __hip_atomic_store(p, v, __ATOMIC_RELAXED, __HIP_MEMORY_SCOPE_AGENT);
}
DEVFN unsigned at_ld32(const unsigned* p) {
    return __hip_atomic_load(p, __ATOMIC_RELAXED, __HIP_MEMORY_SCOPE_AGENT);
}
DEVFN unsigned long long at_ld64(const unsigned long long* p) {
    return __hip_atomic_load(p, __ATOMIC_RELAXED, __HIP_MEMORY_SCOPE_AGENT);
}
DEVFN void spin4(int* f) {
    unsigned g = 0;
    while (__hip_atomic_load(f, __ATOMIC_ACQUIRE, __HIP_MEMORY_SCOPE_AGENT) < 4) {
        __builtin_amdgcn_s_sleep(1);
        if (++g > (1u << 24)) break;   // safety valve: fail fast, never hang
    }
}

struct SrcPtrs { const void* p[26]; };
struct WsPtrs {
    ushort_t *wcfg, *bcfg, *eh, *ew, *es, *wis, *bis, *wes, *vds, *bvds,
             *whh, *wih, *bih, *bhh, *wdt, *bdt, *wd2t, *vdt, *bvdt,
             *wihd, *whhd, *bihd, *bhhd;
};

// ---------------------------------------------------------------------------
__global__ void k_detect(const void* probe, int* flag) {
    if (threadIdx.x == 0 && blockIdx.x == 0) {
        const ushort_t* u = (const ushort_t*)probe;
        int ok = 1;
        for (int i = 0; i < 16; ++i) {
            ushort_t v = u[2 * i];
            int e = (v >> 7) & 0xFF;
            if (!(v == 0 || (e >= 96 && e <= 126))) ok = 0;
        }
        *flag = ok;
    }
}

__global__ void k_zero(int* p, long n) {
    long i = (long)blockIdx.x * 256 + threadIdx.x;
    if (i < n) p[i] = 0;
}

// ---------------------------------------------------------------------------
__global__ __launch_bounds__(256) void k_cvt(SrcPtrs sp, WsPtrs wp, const int* flagp) {
    int bf = *flagp;
    const void* src = nullptr; ushort_t* dst = nullptr; long n = 0;
    switch (blockIdx.x) {
        case 0:  src = sp.p[3];  dst = wp.wcfg; n = 320;    break;
        case 1:  src = sp.p[4];  dst = wp.bcfg; n = 10;     break;
        case 2:  src = sp.p[5];  dst = wp.eh;   n = 120;    break;
        case 3:  src = sp.p[6];  dst = wp.ew;   n = 24;     break;
        case 4:  src = sp.p[7];  dst = wp.es;   n = 15;     break;
        case 5:  src = sp.p[16]; dst = wp.wis;  n = 65536;  break;
        case 6:  src = sp.p[17]; dst = wp.bis;  n = 256;    break;
        case 8:  src = sp.p[19]; dst = wp.vds;  n = 256;    break;
        case 9:  src = sp.p[20]; dst = wp.bvds; n = 1;      break;
        case 12: src = sp.p[10]; dst = wp.bih;  n = 1024;   break;
        case 13: src = sp.p[11]; dst = wp.bhh;  n = 1024;   break;
        case 14: src = sp.p[21]; dst = wp.wdt;  n = 65536;  break;
        case 15: src = sp.p[22]; dst = wp.bdt;  n = 256;    break;
        case 16: src = sp.p[23]; dst = wp.wd2t; n = 512;    break;
        case 17: src = sp.p[24]; dst = wp.vdt;  n = 256;    break;
        case 18: src = sp.p[25]; dst = wp.bvdt; n = 1;      break;
        case 19: src = sp.p[12]; dst = wp.wihd; n = 1028;   break;
        case 20: src = sp.p[13]; dst = wp.whhd; n = 4;      break;
        case 21: src = sp.p[14]; dst = wp.bihd; n = 4;      break;
        case 22: src = sp.p[15]; dst = wp.bhhd; n = 4;      break;
        default: return;
    }
    for (long i = threadIdx.x; i < n; i += 256) {
        float v = bf ? bs2f(((const ushort_t*)src)[i]) : ((const float*)src)[i];
        dst[i] = f2bs(v);
    }
}

// ---------------------------------------------------------------------------
// k_permA: y=0: Whh -> fragment-major; y=1: Wih -> plain bf16 (AX GEMM input).
// ---------------------------------------------------------------------------
__global__ __launch_bounds__(256) void k_permA(
    const void* whh_src, const void* wih_src,
    ushort_t* whhp, ushort_t* wihb, const int* flagp)
{
    int bf = *flagp;
    long base = (long)blockIdx.x * 2048;
    if (blockIdx.y == 1) {
#pragma unroll
        for (int ii = 0; ii < 8; ++ii) {
            long p = base + threadIdx.x + ii * 256;
            wihb[p] = f2bs(gload(wih_src, p, bf));
        }
        return;
    }
#pragma unroll
    for (int ii = 0; ii < 8; ++ii) {
        long p = base + threadIdx.x + ii * 256;
        int c = (int)(p >> 9), l = (int)((p >> 3) & 63), e = (int)(p & 7);
        int w = c >> 5, kk = (c >> 2) & 7, g = c & 3;
        int q = l >> 4, ln = l & 15;
        long si = (long)(g * 256 + w * 16 + ln) * 256 + kk * 32 + q * 8 + e;
        whhp[p] = f2bs(gload(whh_src, si, bf));
    }
}

// ---------------------------------------------------------------------------
__global__ __launch_bounds__(256) void k_permB(
    const void* wes_src, ushort_t* wesp, const int* flagp)
{
    int bf = *flagp;
    long base = (long)blockIdx.x * 2048;
#pragma unroll
    for (int ii = 0; ii < 8; ++ii) {
        long p = base + threadIdx.x + ii * 256;
        int c = (int)(p >> 9), l = (int)((p >> 3) & 63), e = (int)(p & 7);
        int w = c >> 4, kk = c & 15;
        int q = l >> 4, ln = l & 15;
        long si = (long)(w * 16 + ln) * 512 + kk * 32 + q * 8 + e;
        wesp[p] = f2bs(gload(wes_src, si, bf));
    }
}

// ---------------------------------------------------------------------------
__global__ __launch_bounds__(256) void k_build(
    const void* __restrict__ pq, const void* __restrict__ cfg_in,
    const int* __restrict__ timei, WsPtrs wp, const int* __restrict__ flagp,
    ushort_t* __restrict__ inputs)
{
    int bf = *flagp;
    int ch = threadIdx.x;
    for (int rr = 0; rr < 4; ++rr) {
        long row = (long)blockIdx.x * 4 + rr;
        float v;
        if (ch < 235) {
            v = gload(pq, row * 235 + ch, bf);
        } else if (ch < 245) {
            int j = ch - 235;
            float acc = bs2f(wp.bcfg[j]);
            for (int k = 0; k < 32; ++k)
                acc += gload(cfg_in, row * 32 + k, bf) * bs2f(wp.wcfg[j * 32 + k]);
            v = acc;
        } else if (ch < 250) {
            v = bs2f(wp.eh[timei[row * 3 + 0] * 5 + (ch - 245)]);
        } else if (ch < 253) {
            v = bs2f(wp.ew[timei[row * 3 + 1] * 3 + (ch - 250)]);
        } else {
            v = bs2f(wp.es[timei[row * 3 + 2] * 3 + (ch - 253)]);
        }
        inputs[row * 256 + ch] = f2bs(v);
    }
}

// ---------------------------------------------------------------------------
// k_gemm: out = A @ W.T (+ bias). 128x128 tiles, BK=32. (unchanged, proven)
// ---------------------------------------------------------------------------
__global__ __launch_bounds__(256) void k_gemm(
    const ushort_t* __restrict__ A, const ushort_t* __restrict__ W,
    const ushort_t* __restrict__ bias, ushort_t* __restrict__ out,
    int ostride, int gatherB)
{
    const int K = 256;
    __shared__ alignas(16) ushort_t At[128][40];
    __shared__ alignas(16) ushort_t Bt[128][40];

    int tid  = threadIdx.x;
    int lane = tid & 63, wave = tid >> 6;
    int wm = wave >> 1, wn = wave & 1;
    int q = lane >> 4, ln = lane & 15;
    long mbase = (long)blockIdx.x * 128;

    floatx4 acc[4][4];
#pragma unroll
    for (int i = 0; i < 4; ++i)
#pragma unroll
        for (int j = 0; j < 4; ++j) acc[i][j] = (floatx4){0.f, 0.f, 0.f, 0.f};

    for (int k0 = 0; k0 < K; k0 += 32) {
        __syncthreads();
#pragma unroll
        for (int it = 0; it < 2; ++it) {
            int c = tid + it * 256;
            int r = c >> 2, kc = (c & 3) * 8;
            int wrow = gatherB ? (((r & 3) << 8) + ((int)blockIdx.y << 5) + (r >> 2))
                               : ((int)blockIdx.y * 128 + r);
            *reinterpret_cast<short8*>(&At[r][kc]) = ld8(&A[(mbase + r) * K + k0 + kc]);
            *reinterpret_cast<short8*>(&Bt[r][kc]) = ld8(&W[(long)wrow * K + k0 + kc]);
        }
        __syncthreads();
        short8 af[4];
#pragma unroll
        for (int mt = 0; mt < 4; ++mt)
            af[mt] = *reinterpret_cast<const short8*>(&At[wm * 64 + mt * 16 + ln][q * 8]);
#pragma unroll
        for (int nt = 0; nt < 4; ++nt) {
            short8 bf = *reinterpret_cast<const short8*>(&Bt[wn * 64 + nt * 16 + ln][q * 8]);
#pragma unroll
            for (int mt = 0; mt < 4; ++mt)
                acc[mt][nt] = __builtin_amdgcn_mfma_f32_16x16x32_bf16(af[mt], bf, acc[mt][nt], 0, 0, 0);
        }
    }

#pragma unroll
    for (int mt = 0; mt < 4; ++mt)
#pragma unroll
        for (int nt = 0; nt < 4; ++nt)
#pragma unroll
            for (int reg = 0; reg < 4; ++reg) {
                long row = mbase + wm * 64 + mt * 16 + q * 4 + reg;
                int  col = (int)blockIdx.y * 128 + wn * 64 + nt * 16 + ln;
                float bv = bias ? bs2f(bias[col]) : 0.f;
                out[row * (long)ostride + col] = f2bs(acc[mt][nt][reg] + bv);
            }
}

// ---------------------------------------------------------------------------
// k_encoder: 256 blocks (64 rowgroups x 4 col-quarters) x 256 thr (4 waves).
// Block (rg,cq): rows [rg*16..+16), cols [cq*64..+64). Wave wv owns cols
// [cq*64+wv*16..+16) == global wave id w' = cq*4+wv of the old layout.
// Weight stream 192KB/step via per-wave 4-slot global_load_lds ring,
// strict vmcnt(3). Quad-exchanges per step via agent atomics (see header).
// ---------------------------------------------------------------------------
#define MFMA16(a, b, c) __builtin_amdgcn_mfma_f32_16x16x32_bf16((a), (b), (c), 0, 0, 0)

__global__ __launch_bounds__(256) void k_encoder(
    const ushort_t* __restrict__ wi, const ushort_t* __restrict__ ax,
    WsPtrs wp, ushort_t* __restrict__ mid, ushort_t* __restrict__ cx,
    float* __restrict__ apx, int* __restrict__ fA, int* __restrict__ fH)
{
    __shared__ ushort_t wring[4][4][512];             // 16 KB DMA ring
    __shared__ alignas(16) ushort_t hcb[16][520];     // 16.25 KB [h|c] state
    __shared__ alignas(16) float aPartL[4][20];       // per-wave attn partials
    __shared__ float apxL[4][16];                     // gathered quad partials

    int tid  = threadIdx.x;
    int lane = tid & 63, wv = tid >> 6;               // wv in [0,4)
    int q = lane >> 4, ln = lane & 15;
    int rg = (int)blockIdx.x >> 2, cq = (int)blockIdx.x & 3;
    int wprime = cq * 4 + wv;
    int u = cq * 64 + wv * 16 + ln;                   // owned column
    long row0 = (long)rg * 16;

    for (int i = tid; i < 16 * 520; i += 256) ((ushort_t*)hcb)[i] = 0;

    // per-thread invariants
    float bc0 = bs2f(wp.bih[u])       + bs2f(wp.bhh[u]);
    float bc1 = bs2f(wp.bih[256 + u]) + bs2f(wp.bhh[256 + u]);
    float bc2 = bs2f(wp.bih[512 + u]) + bs2f(wp.bhh[512 + u]);
    float bc3 = bs2f(wp.bih[768 + u]) + bs2f(wp.bhh[768 + u]);
    float vds = bs2f(wp.vds[u]);
    float bVd = bs2f(wp.bvds[0]);

    const ushort_t* wesW = wp.wes + ((long)wprime << 13) + lane * 8;  // 16 chunks
    const ushort_t* whhW = wp.whh + ((long)wprime << 14) + lane * 8;  // 32 chunks

    const ushort_t* wiB[4]; const ushort_t* axB[4];
#pragma unroll
    for (int reg = 0; reg < 4; ++reg) {
        long rw = (row0 + q * 4 + reg) * 96;
        wiB[reg] = wi + rw * 256 + u;
        axB[reg] = ax + rw * 1024 + u * 4;
    }

    float creg[4] = {0.f, 0.f, 0.f, 0.f};
    __syncthreads();

    // ---- ring prologue: chunks 0..3 (wes) in flight
#pragma unroll
    for (int j = 0; j < 4; ++j)
        gload_lds16(wesW + (j << 9), &wring[wv][j][0]);

    for (int t = 0; t < 96; ++t) {
        // ---- extras: ax (4x8B) + wi (4x2B) plain loads
        short4v axv[4]; float wiv[4];
#pragma unroll
        for (int reg = 0; reg < 4; ++reg) {
            axv[reg] = *reinterpret_cast<const short4v*>(axB[reg] + (long)t * 1024);
            wiv[reg] = bs2f(wiB[reg][(long)t * 256]);
        }

        // ---- attn matvec: K=512 over [h|c], chunks 0..15 (wes)
        floatx4 acc1 = (floatx4){0.f, 0.f, 0.f, 0.f};
#pragma unroll
        for (int kk = 0; kk < 16; ++kk) {
            VW3();
            short8 bw = ld8(&wring[wv][kk & 3][lane * 8]);
            short8 af = ld8(&hcb[ln][kk * 32 + q * 8]);
            acc1 = MFMA16(af, bw, acc1);
            gload_lds16(chunk_ptr(wesW, whhW, kk + 4), &wring[wv][kk & 3][0]);
        }

        // ---- attn epilogue: tanh, scale, reduce over the 16 ln lanes
        float p4[4];
#pragma unroll
        for (int reg = 0; reg < 4; ++reg)
            p4[reg] = ftanh(acc1[reg] + wiv[reg]) * vds;
#pragma unroll
        for (int m = 1; m < 16; m <<= 1) {
#pragma unroll
            for (int reg = 0; reg < 4; ++reg) p4[reg] += __shfl_xor(p4[reg], m, 64);
        }
        if (ln == 0) {
            floatx4 pv = {p4[0], p4[1], p4[2], p4[3]};
            *reinterpret_cast<floatx4*>(&aPartL[wv][q * 4]) = pv;
        }

        // ---- gates: aH = h@Whh.T; chunks 16..47 (whh)
        floatx4 aH[4];
#pragma unroll
        for (int g = 0; g < 4; ++g) aH[g] = (floatx4){0.f, 0.f, 0.f, 0.f};
#pragma unroll
        for (int kk = 0; kk < 8; ++kk) {
            short8 af = ld8(&hcb[ln][kk * 32 + q * 8]);
#pragma unroll
            for (int g = 0; g < 4; ++g) {
                const int j  = 16 + kk * 4 + g;
                const int jn = (j + 4 < 48) ? (j + 4) : (j + 4 - 48); // wraps to next step
                VW3();
                short8 bw = ld8(&wring[wv][j & 3][lane * 8]);
                aH[g] = MFMA16(af, bw, aH[g]);
                gload_lds16(chunk_ptr(wesW, whhW, jn), &wring[wv][j & 3][0]);
            }
        }

        bar_lgkm();   // B1: aPartL visible; all hcb reads of this step done

        // ---- exchange #1: block attn partial -> apx, flag fA, spin (tid 0)
        long qbase = ((long)t * 64 + rg) * 4;         // quad base in apx/flags
        if (tid == 0) {
            float bp[16];
#pragma unroll
            for (int r = 0; r < 16; ++r)
                bp[r] = aPartL[0][r] + aPartL[1][r] + aPartL[2][r] + aPartL[3][r];
#pragma unroll
            for (int r = 0; r < 16; ++r) {
                union { float f; unsigned v; } cvt; cvt.f = bp[r];
                at_st32((unsigned*)&apx[(qbase + cq) * 16 + r], cvt.v);
            }
            __hip_atomic_fetch_add(&fA[t * 64 + rg], 1, __ATOMIC_RELEASE,
                                   __HIP_MEMORY_SCOPE_AGENT);
            spin4(&fA[t * 64 + rg]);
        }
        bar_lgkm();   // B2: quad partials ready
        if (tid < 64) {
            union { float f; unsigned v; } cvt;
            cvt.v = at_ld32((const unsigned*)&apx[(qbase + (tid >> 4)) * 16 + (tid & 15)]);
            apxL[tid >> 4][tid & 15] = cvt.f;
        }
        bar_lgkm();   // B3: apxL ready

        // ---- cell update: rows q*4+reg, col u; h->mid, c->cx (4B packed atomics)
#pragma unroll
        for (int reg = 0; reg < 4; ++reg) {
            float a = bVd + apxL[0][q * 4 + reg] + apxL[1][q * 4 + reg]
                          + apxL[2][q * 4 + reg] + apxL[3][q * 4 + reg];
            float gi = aH[0][reg] + a * bs2f((ushort_t)axv[reg][0]) + bc0;
            float gf = aH[1][reg] + a * bs2f((ushort_t)axv[reg][1]) + bc1;
            float gg = aH[2][reg] + a * bs2f((ushort_t)axv[reg][2]) + bc2;
            float go = aH[3][reg] + a * bs2f((ushort_t)axv[reg][3]) + bc3;
            float c2 = sigm(gf) * creg[reg] + sigm(gi) * ftanh(gg);
            float h2 = sigm(go) * ftanh(c2);
            creg[reg] = c2;
            unsigned hb = f2bs(h2), cb = f2bs(c2);
            unsigned hn = __shfl_down(hb, 1, 64), cn = __shfl_down(cb, 1, 64);
            if ((ln & 1) == 0) {
                long e = ((row0 + q * 4 + reg) * 96 + t) * 256 + u;   // u even
                at_st32((unsigned*)(mid + e), hb | (hn << 16));
                at_st32((unsigned*)(cx  + e), cb | (cn << 16));
            }
        }
        __syncthreads();  // B4: drains vmcnt -> all hc stores retired (release)
        if (tid == 0) {
            __hip_atomic_fetch_add(&fH[t * 64 + rg], 1, __ATOMIC_RELEASE,
                                   __HIP_MEMORY_SCOPE_AGENT);
            if (t < 95) spin4(&fH[t * 64 + rg]);
        }
        if (t < 95) {
            bar_lgkm();   // B5: quad h,c published
            // ---- gather full 16x256 h,c into hcb (8B agent loads)
#pragma unroll
            for (int k = 0; k < 4; ++k) {
                int unit = tid + k * 256;             // 1024 units of 4 cols
                int r = unit >> 6, c4 = (unit & 63) * 4;
                long e = ((row0 + r) * 96 + t) * 256 + c4;
                unsigned long long hv = at_ld64((const unsigned long long*)(mid + e));
                unsigned long long cv = at_ld64((const unsigned long long*)(cx + e));
                *reinterpret_cast<unsigned long long*>(&hcb[r][c4])       = hv;
                *reinterpret_cast<unsigned long long*>(&hcb[r][256 + c4]) = cv;
            }
            bar_lgkm();   // B6: hcb holds (h_{t+1}, c_{t+1})
        }
    }

    asm volatile("s_waitcnt vmcnt(0)" ::: "memory");  // retire dangling refills
}

// ---------------------------------------------------------------------------
// k_decoder: 1024 blocks (one batch row), 256 thr, 16 sequential steps.
// ---------------------------------------------------------------------------
__global__ __launch_bounds__(256) void k_decoder(
    const ushort_t* __restrict__ mid, const ushort_t* __restrict__ wd,
    WsPtrs wp, const int* __restrict__ flagp, void* __restrict__ out)
{
    __shared__ ushort_t wdl[96][264];
    __shared__ float qL[256], aLs[96], ctxL[256], VdtL[256], gL[4];
    __shared__ float st[3];

    int tid = threadIdx.x;
    long b = blockIdx.x;
    int bf = *flagp;

    for (int c = tid; c < 96 * 256; c += 256) {
        int tp = c >> 8, chn = c & 255;
        wdl[tp][chn] = wd[(b * 96 + tp) * 256 + chn];
    }
    qL[tid] = 0.f; ctxL[tid] = 0.f;
    if (tid < 96) aLs[tid] = 0.f;
    if (tid < 4)  gL[tid] = 0.f;
    VdtL[tid] = bs2f(wp.vdt[tid]);
    if (tid == 0) {
        st[0] = 0.f; st[1] = 0.f;
        st[2] = bs2f(mid[(b * 96 + 95) * 256 + 2]);
    }
    float bVdt = bs2f(wp.bvdt[0]);
    float w2a = bs2f(wp.wd2t[tid * 2]), w2b = bs2f(wp.wd2t[tid * 2 + 1]);
    __syncthreads();

    for (int s = 0; s < 16; ++s) {
        float hi = st[0], ci = st[1], prev = st[2];
        qL[tid] = hi * w2a + ci * w2b;
        __syncthreads();
        {   // attn scores: wave v, lanes split the 256-dot
            int v = tid >> 6, l = tid & 63;
            for (int tp = v; tp < 96; tp += 4) {
                float sacc = 0.f;
#pragma unroll
                for (int e = 0; e < 4; ++e) {
                    int u = l * 4 + e;
                    sacc += ftanh(qL[u] + bs2f(wdl[tp][u])) * VdtL[u];
                }
#pragma unroll
                for (int m = 1; m < 64; m <<= 1) sacc += __shfl_xor(sacc, m, 64);
                if (l == 0) aLs[tp] = sacc + bVdt;
            }
        }
        __syncthreads();
        {
            float acc = 0.f;
            for (int tp = 0; tp < 96; ++tp)
                acc += aLs[tp] * bs2f(mid[(b * 96 + tp) * 256 + tid]);
            ctxL[tid] = acc;
        }
        __syncthreads();
        {   // gates: wave g computes gate g; lanes split the ctx-dot
            int g = tid >> 6, k = tid & 63;
            float part = 0.f;
#pragma unroll
            for (int e = 0; e < 4; ++e) {
                int u = k + e * 64;
                part += bs2f(wp.wihd[g * 257 + u]) * ctxL[u];
            }
#pragma unroll
            for (int m = 1; m < 64; m <<= 1) part += __shfl_xor(part, m, 64);
            if (k == 0)
                gL[g] = part + bs2f(wp.bihd[g]) + bs2f(wp.bhhd[g])
                      + bs2f(wp.whhd[g]) * hi + bs2f(wp.wihd[g * 257 + 256]) * prev;
        }
        __syncthreads();
        if (tid == 0) {
            float c2 = sigm(gL[1]) * ci + sigm(gL[0]) * ftanh(gL[2]);
            float h2 = sigm(gL[3]) * ftanh(c2);
            st[0] = h2; st[1] = c2; st[2] = h2;
            long oi = b * 16 + s;
            if (bf) ((ushort_t*)out)[oi] = f2bs(h2);
            else    ((float*)out)[oi] = h2;
        }
        __syncthreads();
    }
}

// ---------------------------------------------------------------------------
extern "C" void kernel_launch(void* const* d_in, const int* in_sizes, int n_in,
                              void* d_out, int out_size, void* d_ws, size_t ws_size,
                              hipStream_t stream)
{
    const long MT = 1024L * 96;   // 98304 rows

    int* flagp = (int*)d_ws;
    ushort_t* base = (ushort_t*)((char*)d_ws + 256);

    SrcPtrs sp;
    for (int i = 0; i < 26; ++i) sp.p[i] = d_in[i];

    static const long sizes[23] = {
        320, 10, 120, 24, 15, 65536, 256, 131072, 256, 1,
        262144, 262144, 1024, 1024, 65536, 256, 512, 256, 1,
        1028, 4, 4, 4
    };
    ushort_t* ptrs[23];
    long off = 0;
    for (int i = 0; i < 23; ++i) {
        ptrs[i] = base + off;
        off += (sizes[i] + 7) & ~7L;   // 16B-aligned layout
    }

    WsPtrs wp;
    wp.wcfg = ptrs[0];  wp.bcfg = ptrs[1];  wp.eh   = ptrs[2];  wp.ew   = ptrs[3];
    wp.es   = ptrs[4];  wp.wis  = ptrs[5];  wp.bis  = ptrs[6];  wp.wes  = ptrs[7];
    wp.vds  = ptrs[8];  wp.bvds = ptrs[9];  wp.whh  = ptrs[10]; wp.wih  = ptrs[11];
    wp.bih  = ptrs[12]; wp.bhh  = ptrs[13]; wp.wdt  = ptrs[14]; wp.bdt  = ptrs[15];
    wp.wd2t = ptrs[16]; wp.vdt  = ptrs[17]; wp.bvdt = ptrs[18]; wp.wihd = ptrs[19];
    wp.whhd = ptrs[20]; wp.bihd = ptrs[21]; wp.bhhd = ptrs[22];

    ushort_t* inputs = base + off;            // MT*256 (dead after GEMMs)
    ushort_t* wib    = inputs + MT * 256;     // MT*256
    ushort_t* midb   = wib + MT * 256;        // MT*256
    ushort_t* axb    = midb + MT * 256;       // MT*1024 (201 MB): AX = x@Wih.T
    ushort_t* wdb    = wib;                   // alias: wi dead after encoder
    ushort_t* cxb    = inputs;                // alias: c-exchange reuses inputs
    float*    apxb   = (float*)(axb + MT * 1024);       // 96*64*4*16 floats
    int*      fAb    = (int*)(apxb + 96L * 64 * 4 * 16);
    int*      fHb    = fAb + 96 * 64;

    k_detect<<<1, 64, 0, stream>>>(d_in[3], flagp);
    k_cvt<<<23, 256, 0, stream>>>(sp, wp, flagp);
    k_permA<<<dim3(128, 2), 256, 0, stream>>>(d_in[9], d_in[8], wp.whh, wp.wih, flagp);
    k_permB<<<64, 256, 0, stream>>>(d_in[18], wp.wes, flagp);
    k_build<<<24576, 256, 0, stream>>>(d_in[0], d_in[1], (const int*)d_in[2],
                                       wp, flagp, inputs);
    k_gemm<<<dim3(768, 2), 256, 0, stream>>>(inputs, wp.wis, wp.bis, wib, 256, 0);
    k_gemm<<<dim3(768, 8), 256, 0, stream>>>(inputs, wp.wih, nullptr, axb, 1024, 1);
    k_zero<<<48, 256, 0, stream>>>(fAb, 2L * 96 * 64);
    k_encoder<<<256, 256, 0, stream>>>(wib, axb, wp, midb, cxb, apxb, fAb, fHb);
    k_gemm<<<dim3(768, 2), 256, 0, stream>>>(midb, wp.wdt, wp.bdt, wdb, 256, 0);
    k_decoder<<<1024, 256, 0, stream>>>(midb, wdb, wp, flagp, d_out);
}

// Round 8
// 2682.357 us; speedup vs baseline: 1.2877x; 1.2877x over previous
//
#include <hip/hip_runtime.h>
#include <hip/hip_bf16.h>

// ---------------------------------------------------------------------------
// Round 14: back to the proven R10 monolithic encoder (1464us), plus:
//   - MERGED fragment sweep: attn h-part and gates read the SAME hc
//     fragments; one pass does 5 MFMAs per fragment (wes_m + whh_4m..4m+3),
//     then 8 attn c-part chunks. Saves 131KB/step of LDS reads and lets
//     gates start before the epilogue/barrier.
//   - DMA ring deepened 4 -> 6 slots (96KB LDS), strict vmcnt(5) waits
//     (safe by in-order retirement; foreign VMEM only makes waits stricter).
//   R13's column-split is reverted: its h,c exchange cost ~400MB HBM traffic
//   (the measured 2.3ms). R8/9/11/12's register ring is dead (allocator).
// ---------------------------------------------------------------------------

typedef unsigned short ushort_t;
using short4v = __attribute__((ext_vector_type(4))) short;   // 4 x bf16
using short8  = __attribute__((ext_vector_type(8))) short;   // 8 x bf16
using floatx4 = __attribute__((ext_vector_type(4))) float;   // MFMA accumulator

#define DEVFN static __device__ __forceinline__

DEVFN float bs2f(ushort_t u) {
    union { float f; unsigned v; } c; c.v = ((unsigned)u) << 16; return c.f;
}
DEVFN ushort_t f2bs(float f) {
    __hip_bfloat16 h = __float2bfloat16(f);
    return *reinterpret_cast<ushort_t*>(&h);
}
DEVFN float gload(const void* p, long i, int bf) {
    if (bf) return bs2f(((const ushort_t*)p)[i]);
    return ((const float*)p)[i];
}
DEVFN float sigm(float x) { return 1.f / (1.f + __expf(-x)); }
DEVFN float ftanh(float x) {
    float t = __expf(-2.f * fabsf(x));
    float r = (1.f - t) / (1.f + t);
    return copysignf(r, x);
}
DEVFN short8 ld8(const ushort_t* p) { return *reinterpret_cast<const short8*>(p); }

// publish LDS writes + barrier WITHOUT draining vmcnt (DMA refills stay live)
DEVFN void bar_lgkm() {
    asm volatile("s_waitcnt lgkmcnt(0)" ::: "memory");
    __builtin_amdgcn_s_barrier();
}

// async global->LDS DMA: 64 lanes x 16B; per-lane global addr, uniform LDS base
DEVFN void gload_lds16(const ushort_t* g, ushort_t* l) {
    typedef const __attribute__((address_space(1))) unsigned int gu32;
    typedef __attribute__((address_space(3))) unsigned int lu32;
    __builtin_amdgcn_global_load_lds((gu32*)g, (lu32*)l, 16, 0, 0);
}

// strict ring wait: slot's refill has exactly 5 younger ring refills when
// consumed; any interleaved foreign VMEM only makes the wait stricter.
#define VW5() asm volatile("s_waitcnt vmcnt(5)" ::: "memory")

// merged stream order, seq j in [0,48):
//   j<40 : m=j/5, r=j%5 ; r==0 -> wes chunk m ; r>0 -> whh chunk 4m+(r-1)
//   j>=40: wes chunk (j-32)   (c-part chunks 8..15)
DEVFN const ushort_t* sptr(const ushort_t* wesW, const ushort_t* whhW, int j) {
    if (j >= 40) return wesW + ((j - 32) << 9);
    int m = j / 5, r = j - m * 5;
    return (r == 0) ? (wesW + (m << 9)) : (whhW + ((4 * m + r - 1) << 9));
}

struct SrcPtrs { const void* p[26]; };
struct WsPtrs {
    // wes/whh hold PERMUTED (fragment-major) data; wih holds PLAIN bf16
    // row-major Wih_e (GEMM input).
    ushort_t *wcfg, *bcfg, *eh, *ew, *es, *wis, *bis, *wes, *vds, *bvds,
             *whh, *wih, *bih, *bhh, *wdt, *bdt, *wd2t, *vdt, *bvdt,
             *wihd, *whhd, *bihd, *bhhd;
};

// ---------------------------------------------------------------------------
__global__ void k_detect(const void* probe, int* flag) {
    if (threadIdx.x == 0 && blockIdx.x == 0) {
        const ushort_t* u = (const ushort_t*)probe;
        int ok = 1;
        for (int i = 0; i < 16; ++i) {
            ushort_t v = u[2 * i];
            int e = (v >> 7) & 0xFF;
            if (!(v == 0 || (e >= 96 && e <= 126))) ok = 0;
        }
        *flag = ok;
    }
}

// ---------------------------------------------------------------------------
// k_cvt: small tensors only (wes/whh/wih are handled by the perm kernels).
// ---------------------------------------------------------------------------
__global__ __launch_bounds__(256) void k_cvt(SrcPtrs sp, WsPtrs wp, const int* flagp) {
    int bf = *flagp;
    const void* src = nullptr; ushort_t* dst = nullptr; long n = 0;
    switch (blockIdx.x) {
        case 0:  src = sp.p[3];  dst = wp.wcfg; n = 320;    break;
        case 1:  src = sp.p[4];  dst = wp.bcfg; n = 10;     break;
        case 2:  src = sp.p[5];  dst = wp.eh;   n = 120;    break;
        case 3:  src = sp.p[6];  dst = wp.ew;   n = 24;     break;
        case 4:  src = sp.p[7];  dst = wp.es;   n = 15;     break;
        case 5:  src = sp.p[16]; dst = wp.wis;  n = 65536;  break;
        case 6:  src = sp.p[17]; dst = wp.bis;  n = 256;    break;
        case 8:  src = sp.p[19]; dst = wp.vds;  n = 256;    break;
        case 9:  src = sp.p[20]; dst = wp.bvds; n = 1;      break;
        case 12: src = sp.p[10]; dst = wp.bih;  n = 1024;   break;
        case 13: src = sp.p[11]; dst = wp.bhh;  n = 1024;   break;
        case 14: src = sp.p[21]; dst = wp.wdt;  n = 65536;  break;
        case 15: src = sp.p[22]; dst = wp.bdt;  n = 256;    break;
        case 16: src = sp.p[23]; dst = wp.wd2t; n = 512;    break;
        case 17: src = sp.p[24]; dst = wp.vdt;  n = 256;    break;
        case 18: src = sp.p[25]; dst = wp.bvdt; n = 1;      break;
        case 19: src = sp.p[12]; dst = wp.wihd; n = 1028;   break;
        case 20: src = sp.p[13]; dst = wp.whhd; n = 4;      break;
        case 21: src = sp.p[14]; dst = wp.bihd; n = 4;      break;
        case 22: src = sp.p[15]; dst = wp.bhhd; n = 4;      break;
        default: return;
    }
    for (long i = threadIdx.x; i < n; i += 256) {
        float v = bf ? bs2f(((const ushort_t*)src)[i]) : ((const float*)src)[i];
        dst[i] = f2bs(v);
    }
}

// ---------------------------------------------------------------------------
// k_permA: y=0: Whh (1024x256 row-major) -> fragment-major (encoder layout).
//          y=1: Wih -> PLAIN bf16 copy (row-major; consumed by the AX GEMM).
// ---------------------------------------------------------------------------
__global__ __launch_bounds__(256) void k_permA(
    const void* whh_src, const void* wih_src,
    ushort_t* whhp, ushort_t* wihb, const int* flagp)
{
    int bf = *flagp;
    long base = (long)blockIdx.x * 2048;
    if (blockIdx.y == 1) {
#pragma unroll
        for (int ii = 0; ii < 8; ++ii) {
            long p = base + threadIdx.x + ii * 256;
            wihb[p] = f2bs(gload(wih_src, p, bf));
        }
        return;
    }
#pragma unroll
    for (int ii = 0; ii < 8; ++ii) {
        long p = base + threadIdx.x + ii * 256;
        int c = (int)(p >> 9), l = (int)((p >> 3) & 63), e = (int)(p & 7);
        int w = c >> 5, kk = (c >> 2) & 7, g = c & 3;
        int q = l >> 4, ln = l & 15;
        long si = (long)(g * 256 + w * 16 + ln) * 256 + kk * 32 + q * 8 + e;
        whhp[p] = f2bs(gload(whh_src, si, bf));
    }
}

// ---------------------------------------------------------------------------
// k_permB: Wes (256x512 row-major) -> fragment-major. c = w*16 + kk (kk 0..15).
// ---------------------------------------------------------------------------
__global__ __launch_bounds__(256) void k_permB(
    const void* wes_src, ushort_t* wesp, const int* flagp)
{
    int bf = *flagp;
    long base = (long)blockIdx.x * 2048;
#pragma unroll
    for (int ii = 0; ii < 8; ++ii) {
        long p = base + threadIdx.x + ii * 256;
        int c = (int)(p >> 9), l = (int)((p >> 3) & 63), e = (int)(p & 7);
        int w = c >> 4, kk = c & 15;
        int q = l >> 4, ln = l & 15;
        long si = (long)(w * 16 + ln) * 512 + kk * 32 + q * 8 + e;
        wesp[p] = f2bs(gload(wes_src, si, bf));
    }
}

// ---------------------------------------------------------------------------
// k_build: features. 24576 blocks x 256 thr, 4 rows/block.
// ---------------------------------------------------------------------------
__global__ __launch_bounds__(256) void k_build(
    const void* __restrict__ pq, const void* __restrict__ cfg_in,
    const int* __restrict__ timei, WsPtrs wp, const int* __restrict__ flagp,
    ushort_t* __restrict__ inputs)
{
    int bf = *flagp;
    int ch = threadIdx.x;
    for (int rr = 0; rr < 4; ++rr) {
        long row = (long)blockIdx.x * 4 + rr;
        float v;
        if (ch < 235) {
            v = gload(pq, row * 235 + ch, bf);
        } else if (ch < 245) {
            int j = ch - 235;
            float acc = bs2f(wp.bcfg[j]);
            for (int k = 0; k < 32; ++k)
                acc += gload(cfg_in, row * 32 + k, bf) * bs2f(wp.wcfg[j * 32 + k]);
            v = acc;
        } else if (ch < 250) {
            v = bs2f(wp.eh[timei[row * 3 + 0] * 5 + (ch - 245)]);
        } else if (ch < 253) {
            v = bs2f(wp.ew[timei[row * 3 + 1] * 3 + (ch - 250)]);
        } else {
            v = bs2f(wp.es[timei[row * 3 + 2] * 3 + (ch - 253)]);
        }
        inputs[row * 256 + ch] = f2bs(v);
    }
}

// ---------------------------------------------------------------------------
// k_gemm: out = A @ W.T (+ bias). A:(98304x256), W row-major ws bf16, K=256.
// 128x128 tiles, BK=32, 4 waves of 64x64.
// ---------------------------------------------------------------------------
__global__ __launch_bounds__(256) void k_gemm(
    const ushort_t* __restrict__ A, const ushort_t* __restrict__ W,
    const ushort_t* __restrict__ bias, ushort_t* __restrict__ out,
    int ostride, int gatherB)
{
    const int K = 256;
    __shared__ alignas(16) ushort_t At[128][40];
    __shared__ alignas(16) ushort_t Bt[128][40];

    int tid  = threadIdx.x;
    int lane = tid & 63, wave = tid >> 6;
    int wm = wave >> 1, wn = wave & 1;
    int q = lane >> 4, ln = lane & 15;
    long mbase = (long)blockIdx.x * 128;

    floatx4 acc[4][4];
#pragma unroll
    for (int i = 0; i < 4; ++i)
#pragma unroll
        for (int j = 0; j < 4; ++j) acc[i][j] = (floatx4){0.f, 0.f, 0.f, 0.f};

    for (int k0 = 0; k0 < K; k0 += 32) {
        __syncthreads();
#pragma unroll
        for (int it = 0; it < 2; ++it) {
            int c = tid + it * 256;
            int r = c >> 2, kc = (c & 3) * 8;
            int wrow = gatherB ? (((r & 3) << 8) + ((int)blockIdx.y << 5) + (r >> 2))
                               : ((int)blockIdx.y * 128 + r);
            *reinterpret_cast<short8*>(&At[r][kc]) = ld8(&A[(mbase + r) * K + k0 + kc]);
            *reinterpret_cast<short8*>(&Bt[r][kc]) = ld8(&W[(long)wrow * K + k0 + kc]);
        }
        __syncthreads();
        short8 af[4];
#pragma unroll
        for (int mt = 0; mt < 4; ++mt)
            af[mt] = *reinterpret_cast<const short8*>(&At[wm * 64 + mt * 16 + ln][q * 8]);
#pragma unroll
        for (int nt = 0; nt < 4; ++nt) {
            short8 bf = *reinterpret_cast<const short8*>(&Bt[wn * 64 + nt * 16 + ln][q * 8]);
#pragma unroll
            for (int mt = 0; mt < 4; ++mt)
                acc[mt][nt] = __builtin_amdgcn_mfma_f32_16x16x32_bf16(af[mt], bf, acc[mt][nt], 0, 0, 0);
        }
    }

#pragma unroll
    for (int mt = 0; mt < 4; ++mt)
#pragma unroll
        for (int nt = 0; nt < 4; ++nt)
#pragma unroll
            for (int reg = 0; reg < 4; ++reg) {
                long row = mbase + wm * 64 + mt * 16 + q * 4 + reg;
                int  col = (int)blockIdx.y * 128 + wn * 64 + nt * 16 + ln;
                float bv = bias ? bs2f(bias[col]) : 0.f;
                out[row * (long)ostride + col] = f2bs(acc[mt][nt][reg] + bv);
            }
}

// ---------------------------------------------------------------------------
// k_encoder: 64 blocks x 1024 thr (16 waves), 16 batch rows/block.
// Weight chunks (48 x 1KB per wave per step) DMA'd via global_load_lds into
// a per-wave 6-slot LDS ring; strict vmcnt(5); refills cross barriers and
// step boundaries. MERGED sweep: per h-fragment m (kk=0..7) do 5 MFMAs
// {attn wes_m, gates whh_4m..4m+3}, then 8 attn c-part chunks; epilogue;
// barA; aval; cell; barC.
// ---------------------------------------------------------------------------
#define MFMA16(a, b, c) __builtin_amdgcn_mfma_f32_16x16x32_bf16((a), (b), (c), 0, 0, 0)

__global__ __launch_bounds__(1024) void k_encoder(
    const ushort_t* __restrict__ wi, const ushort_t* __restrict__ ax,
    WsPtrs wp, ushort_t* __restrict__ mid)
{
    __shared__ ushort_t wring[16][6][512];             // 96 KB DMA ring
    __shared__ alignas(16) ushort_t hcb[2][16][520];   // 33 KB [h|c] dbuf
    __shared__ alignas(16) float aPartT[16][20];       // [wave][row]

    int tid  = threadIdx.x;
    int lane = tid & 63, w = tid >> 6;                 // w in [0,16)
    int q = lane >> 4, ln = lane & 15;
    int u = w * 16 + ln;                               // owned column
    long row0 = (long)blockIdx.x * 16;

    for (int i = tid; i < 2 * 16 * 520; i += 1024) ((ushort_t*)hcb)[i] = 0;

    // per-thread invariants
    float bc0 = bs2f(wp.bih[u])       + bs2f(wp.bhh[u]);
    float bc1 = bs2f(wp.bih[256 + u]) + bs2f(wp.bhh[256 + u]);
    float bc2 = bs2f(wp.bih[512 + u]) + bs2f(wp.bhh[512 + u]);
    float bc3 = bs2f(wp.bih[768 + u]) + bs2f(wp.bhh[768 + u]);
    float vds = bs2f(wp.vds[u]);
    float bVd = bs2f(wp.bvds[0]);

    const ushort_t* wesW = wp.wes + ((long)w << 13) + lane * 8;   // 16 chunks
    const ushort_t* whhW = wp.whh + ((long)w << 14) + lane * 8;   // 32 chunks

    const ushort_t* wiB[4]; const ushort_t* axB[4];
#pragma unroll
    for (int reg = 0; reg < 4; ++reg) {
        long rw = (row0 + q * 4 + reg) * 96;
        wiB[reg] = wi + rw * 256 + u;
        axB[reg] = ax + rw * 1024 + u * 4;
    }
    int mr = tid >> 6, mc = (tid & 63) * 4;            // mid-writer mapping
    ushort_t* midB = mid + (row0 + mr) * 96 * 256 + mc;

    float creg[4] = {0.f, 0.f, 0.f, 0.f};
    __syncthreads();

    // ---- ring prologue: seqs 0..5 in flight
#pragma unroll
    for (int j = 0; j < 6; ++j)
        gload_lds16(sptr(wesW, whhW, j), &wring[w][j][0]);

    for (int t = 0; t < 96; ++t) {
        ushort_t (*R)[520]  = hcb[t & 1];
        ushort_t (*Wb)[520] = hcb[(t & 1) ^ 1];

        // ---- mid write of step t-1 (t=0: dummy to slot 95, overwritten at end)
        {
            long toff = (long)(t > 0 ? t - 1 : 95) * 256;
            uint2 hv = *reinterpret_cast<const uint2*>(&R[mr][mc]);
            *reinterpret_cast<uint2*>(midB + toff) = hv;
        }
        // ---- ax (4x8B) + wi (4x2B) prefetch
        short4v axv[4]; float wiv[4];
#pragma unroll
        for (int reg = 0; reg < 4; ++reg) {
            axv[reg] = *reinterpret_cast<const short4v*>(axB[reg] + (long)t * 1024);
            wiv[reg] = bs2f(wiB[reg][(long)t * 256]);
        }

        floatx4 acc1 = (floatx4){0.f, 0.f, 0.f, 0.f};
        floatx4 aH[4];
#pragma unroll
        for (int g = 0; g < 4; ++g) aH[g] = (floatx4){0.f, 0.f, 0.f, 0.f};

        // ---- merged sweep phase 1: m=0..7, one h-fragment -> 5 MFMAs
#pragma unroll
        for (int m = 0; m < 8; ++m) {
            short8 af = ld8(&R[ln][m * 32 + q * 8]);
            {
                const int i = 5 * m;                    // wes_m -> attn
                VW5();
                short8 bw = ld8(&wring[w][i % 6][lane * 8]);
                acc1 = MFMA16(af, bw, acc1);
                gload_lds16(sptr(wesW, whhW, (i + 6) % 48), &wring[w][i % 6][0]);
            }
#pragma unroll
            for (int g = 0; g < 4; ++g) {
                const int i = 5 * m + 1 + g;            // whh_{4m+g} -> gate g
                VW5();
                short8 bw = ld8(&wring[w][i % 6][lane * 8]);
                aH[g] = MFMA16(af, bw, aH[g]);
                gload_lds16(sptr(wesW, whhW, (i + 6) % 48), &wring[w][i % 6][0]);
            }
        }
        // ---- merged sweep phase 2: attn c-part, chunks wes_8..15
#pragma unroll
        for (int kk = 8; kk < 16; ++kk) {
            const int i = kk + 32;                      // seqs 40..47
            short8 af = ld8(&R[ln][kk * 32 + q * 8]);
            VW5();
            short8 bw = ld8(&wring[w][i % 6][lane * 8]);
            acc1 = MFMA16(af, bw, acc1);
            gload_lds16(sptr(wesW, whhW, (i + 6) % 48), &wring[w][i % 6][0]);
        }

        // ---- attn epilogue: tanh, scale, reduce over 16 ln lanes
        float p4[4];
#pragma unroll
        for (int reg = 0; reg < 4; ++reg)
            p4[reg] = ftanh(acc1[reg] + wiv[reg]) * vds;
#pragma unroll
        for (int m = 1; m < 16; m <<= 1) {
#pragma unroll
            for (int reg = 0; reg < 4; ++reg) p4[reg] += __shfl_xor(p4[reg], m, 64);
        }
        if (ln == 0) {
            floatx4 pv = {p4[0], p4[1], p4[2], p4[3]};
            *reinterpret_cast<floatx4*>(&aPartT[w][q * 4]) = pv;
        }
        bar_lgkm();   // barrier A: aPartT visible (DMA refills stay live)

        // ---- aval: per-row sum of 16 wave partials (broadcast b128 reads)
        floatx4 av = {bVd, bVd, bVd, bVd};
#pragma unroll
        for (int ww = 0; ww < 16; ++ww)
            av += *reinterpret_cast<const floatx4*>(&aPartT[ww][q * 4]);

        // ---- cell update: rows q*4+reg, col u; write into Wb
#pragma unroll
        for (int reg = 0; reg < 4; ++reg) {
            float a  = av[reg];
            float gi = aH[0][reg] + a * bs2f((ushort_t)axv[reg][0]) + bc0;
            float gf = aH[1][reg] + a * bs2f((ushort_t)axv[reg][1]) + bc1;
            float gg = aH[2][reg] + a * bs2f((ushort_t)axv[reg][2]) + bc2;
            float go = aH[3][reg] + a * bs2f((ushort_t)axv[reg][3]) + bc3;
            float c2 = sigm(gf) * creg[reg] + sigm(gi) * ftanh(gg);
            float h2 = sigm(go) * ftanh(c2);
            creg[reg] = c2;
            int r = q * 4 + reg;
            Wb[r][u] = f2bs(h2);
            Wb[r][256 + u] = f2bs(c2);
        }
        bar_lgkm();   // barrier C: new state published
    }

    // drain leftover DMA refills, then the real final mid write (h_96)
    asm volatile("s_waitcnt vmcnt(0)" ::: "memory");
    {
        uint2 hv = *reinterpret_cast<const uint2*>(&hcb[0][mr][mc]);
        *reinterpret_cast<uint2*>(midB + 95L * 256) = hv;
    }
}

// ---------------------------------------------------------------------------
// k_decoder: 1024 blocks (one batch row), 256 thr, 16 sequential steps.
// ---------------------------------------------------------------------------
__global__ __launch_bounds__(256) void k_decoder(
    const ushort_t* __restrict__ mid, const ushort_t* __restrict__ wd,
    WsPtrs wp, const int* __restrict__ flagp, void* __restrict__ out)
{
    __shared__ ushort_t wdl[96][264];
    __shared__ float qL[256], aLs[96], ctxL[256], VdtL[256], gL[4];
    __shared__ float st[3];

    int tid = threadIdx.x;
    long b = blockIdx.x;
    int bf = *flagp;

    for (int c = tid; c < 96 * 256; c += 256) {
        int tp = c >> 8, chn = c & 255;
        wdl[tp][chn] = wd[(b * 96 + tp) * 256 + chn];
    }
    qL[tid] = 0.f; ctxL[tid] = 0.f;
    if (tid < 96) aLs[tid] = 0.f;
    if (tid < 4)  gL[tid] = 0.f;
    VdtL[tid] = bs2f(wp.vdt[tid]);
    if (tid == 0) {
        st[0] = 0.f; st[1] = 0.f;
        st[2] = bs2f(mid[(b * 96 + 95) * 256 + 2]);
    }
    float bVdt = bs2f(wp.bvdt[0]);
    float w2a = bs2f(wp.wd2t[tid * 2]), w2b = bs2f(wp.wd2t[tid * 2 + 1]);
    __syncthreads();

    for (int s = 0; s < 16; ++s) {
        float hi = st[0], ci = st[1], prev = st[2];
        qL[tid] = hi * w2a + ci * w2b;
        __syncthreads();
        {   // attn scores: wave v, lanes split the 256-dot
            int v = tid >> 6, l = tid & 63;
            for (int tp = v; tp < 96; tp += 4) {
                float sacc = 0.f;
#pragma unroll
                for (int e = 0; e < 4; ++e) {
                    int u = l * 4 + e;
                    sacc += ftanh(qL[u] + bs2f(wdl[tp][u])) * VdtL[u];
                }
#pragma unroll
                for (int m = 1; m < 64; m <<= 1) sacc += __shfl_xor(sacc, m, 64);
                if (l == 0) aLs[tp] = sacc + bVdt;
            }
        }
        __syncthreads();
        {
            float acc = 0.f;
            for (int tp = 0; tp < 96; ++tp)
                acc += aLs[tp] * bs2f(mid[(b * 96 + tp) * 256 + tid]);
            ctxL[tid] = acc;
        }
        __syncthreads();
        {   // gates: wave g computes gate g; lanes split the ctx-dot
            int g = tid >> 6, k = tid & 63;
            float part = 0.f;
#pragma unroll
            for (int e = 0; e < 4; ++e) {
                int u = k + e * 64;
                part += bs2f(wp.wihd[g * 257 + u]) * ctxL[u];
            }
#pragma unroll
            for (int m = 1; m < 64; m <<= 1) part += __shfl_xor(part, m, 64);
            if (k == 0)
                gL[g] = part + bs2f(wp.bihd[g]) + bs2f(wp.bhhd[g])
                      + bs2f(wp.whhd[g]) * hi + bs2f(wp.wihd[g * 257 + 256]) * prev;
        }
        __syncthreads();
        if (tid == 0) {
            float c2 = sigm(gL[1]) * ci + sigm(gL[0]) * ftanh(gL[2]);
            float h2 = sigm(gL[3]) * ftanh(c2);
            st[0] = h2; st[1] = c2; st[2] = h2;
            long oi = b * 16 + s;
            if (bf) ((ushort_t*)out)[oi] = f2bs(h2);
            else    ((float*)out)[oi] = h2;
        }
        __syncthreads();
    }
}

// ---------------------------------------------------------------------------
extern "C" void kernel_launch(void* const* d_in, const int* in_sizes, int n_in,
                              void* d_out, int out_size, void* d_ws, size_t ws_size,
                              hipStream_t stream)
{
    const long MT = 1024L * 96;   // 98304 rows

    int* flagp = (int*)d_ws;
    ushort_t* base = (ushort_t*)((char*)d_ws + 256);

    SrcPtrs sp;
    for (int i = 0; i < 26; ++i) sp.p[i] = d_in[i];

    static const long sizes[23] = {
        320, 10, 120, 24, 15, 65536, 256, 131072, 256, 1,
        262144, 262144, 1024, 1024, 65536, 256, 512, 256, 1,
        1028, 4, 4, 4
    };
    ushort_t* ptrs[23];
    long off = 0;
    for (int i = 0; i < 23; ++i) {
        ptrs[i] = base + off;
        off += (sizes[i] + 7) & ~7L;   // 16B-aligned layout
    }

    WsPtrs wp;
    wp.wcfg = ptrs[0];  wp.bcfg = ptrs[1];  wp.eh   = ptrs[2];  wp.ew   = ptrs[3];
    wp.es   = ptrs[4];  wp.wis  = ptrs[5];  wp.bis  = ptrs[6];  wp.wes  = ptrs[7];
    wp.vds  = ptrs[8];  wp.bvds = ptrs[9];  wp.whh  = ptrs[10]; wp.wih  = ptrs[11];
    wp.bih  = ptrs[12]; wp.bhh  = ptrs[13]; wp.wdt  = ptrs[14]; wp.bdt  = ptrs[15];
    wp.wd2t = ptrs[16]; wp.vdt  = ptrs[17]; wp.bvdt = ptrs[18]; wp.wihd = ptrs[19];
    wp.whhd = ptrs[20]; wp.bihd = ptrs[21]; wp.bhhd = ptrs[22];

    ushort_t* inputs = base + off;            // MT*256
    ushort_t* wib    = inputs + MT * 256;     // MT*256
    ushort_t* midb   = wib + MT * 256;        // MT*256
    ushort_t* axb    = midb + MT * 256;       // MT*1024 (201 MB): AX = x@Wih.T
    ushort_t* wdb    = wib;                   // alias: wi dead after encoder

    k_detect<<<1, 64, 0, stream>>>(d_in[3], flagp);
    k_cvt<<<23, 256, 0, stream>>>(sp, wp, flagp);
    k_permA<<<dim3(128, 2), 256, 0, stream>>>(d_in[9], d_in[8], wp.whh, wp.wih, flagp);
    k_permB<<<64, 256, 0, stream>>>(d_in[18], wp.wes, flagp);
    k_build<<<24576, 256, 0, stream>>>(d_in[0], d_in[1], (const int*)d_in[2],
                                       wp, flagp, inputs);
    k_gemm<<<dim3(768, 2), 256, 0, stream>>>(inputs, wp.wis, wp.bis, wib, 256, 0);
    k_gemm<<<dim3(768, 8), 256, 0, stream>>>(inputs, wp.wih, nullptr, axb, 1024, 1);
    k_encoder<<<64, 1024, 0, stream>>>(wib, axb, wp, midb);
    k_gemm<<<dim3(768, 2), 256, 0, stream>>>(midb, wp.wdt, wp.bdt, wdb, 256, 0);
    k_decoder<<<1024, 256, 0, stream>>>(midb, wdb, wp, flagp, d_out);
}

// Round 9
// 2483.125 us; speedup vs baseline: 1.3910x; 1.0802x over previous
//
#include <hip/hip_runtime.h>
#include <hip/hip_bf16.h>

// ---------------------------------------------------------------------------
// Round 15: 8-wave encoder, 2 column-slices per wave, 12-deep DMA ring.
//   Cross-round accounting showed R7/R10/R14 all stuck at ~790cy/chunk:
//   the 4-6 deep rings never covered L2 latency (per-chunk consume ~40cy
//   -> lookahead 160-240cy < 250-600cy). With 8 waves x 2 slices the ring
//   deepens to 12 (96KB, 96 chunks/wave/step, 96%12=0), lookahead ~480cy,
//   and the hc fragment is column-independent -> one ds_read feeds 2 MFMAs
//   (fragment reads halve). Schedule/barriers/waits = R10's proven pattern;
//   strict vmcnt(11) safe under any foreign-VMEM interleave (in-order
//   retirement). Everything outside k_encoder unchanged.
// ---------------------------------------------------------------------------

typedef unsigned short ushort_t;
using short4v = __attribute__((ext_vector_type(4))) short;   // 4 x bf16
using short8  = __attribute__((ext_vector_type(8))) short;   // 8 x bf16
using floatx4 = __attribute__((ext_vector_type(4))) float;   // MFMA accumulator

#define DEVFN static __device__ __forceinline__

DEVFN float bs2f(ushort_t u) {
    union { float f; unsigned v; } c; c.v = ((unsigned)u) << 16; return c.f;
}
DEVFN ushort_t f2bs(float f) {
    __hip_bfloat16 h = __float2bfloat16(f);
    return *reinterpret_cast<ushort_t*>(&h);
}
DEVFN float gload(const void* p, long i, int bf) {
    if (bf) return bs2f(((const ushort_t*)p)[i]);
    return ((const float*)p)[i];
}
DEVFN float sigm(float x) { return 1.f / (1.f + __expf(-x)); }
DEVFN float ftanh(float x) {
    float t = __expf(-2.f * fabsf(x));
    float r = (1.f - t) / (1.f + t);
    return copysignf(r, x);
}
DEVFN short8 ld8(const ushort_t* p) { return *reinterpret_cast<const short8*>(p); }

// publish LDS writes + barrier WITHOUT draining vmcnt (DMA refills stay live)
DEVFN void bar_lgkm() {
    asm volatile("s_waitcnt lgkmcnt(0)" ::: "memory");
    __builtin_amdgcn_s_barrier();
}

// async global->LDS DMA: 64 lanes x 16B; per-lane global addr, uniform LDS base
DEVFN void gload_lds16(const ushort_t* g, ushort_t* l) {
    typedef const __attribute__((address_space(1))) unsigned int gu32;
    typedef __attribute__((address_space(3))) unsigned int lu32;
    __builtin_amdgcn_global_load_lds((gu32*)g, (lu32*)l, 16, 0, 0);
}

// strict ring wait: consume slot j only after its refill retired. At consume
// of seq j, refills j+1..j+11 are issued (11 younger ring refills); any
// foreign VMEM in between only makes the wait stricter (in-order retirement).
#define VW11() asm volatile("s_waitcnt vmcnt(11)" ::: "memory")

struct SrcPtrs { const void* p[26]; };
struct WsPtrs {
    // wes/whh hold PERMUTED (fragment-major) data; wih holds PLAIN bf16
    // row-major Wih_e (GEMM input).
    ushort_t *wcfg, *bcfg, *eh, *ew, *es, *wis, *bis, *wes, *vds, *bvds,
             *whh, *wih, *bih, *bhh, *wdt, *bdt, *wd2t, *vdt, *bvdt,
             *wihd, *whhd, *bihd, *bhhd;
};

// ---------------------------------------------------------------------------
__global__ void k_detect(const void* probe, int* flag) {
    if (threadIdx.x == 0 && blockIdx.x == 0) {
        const ushort_t* u = (const ushort_t*)probe;
        int ok = 1;
        for (int i = 0; i < 16; ++i) {
            ushort_t v = u[2 * i];
            int e = (v >> 7) & 0xFF;
            if (!(v == 0 || (e >= 96 && e <= 126))) ok = 0;
        }
        *flag = ok;
    }
}

// ---------------------------------------------------------------------------
// k_cvt: small tensors only (wes/whh/wih are handled by the perm kernels).
// ---------------------------------------------------------------------------
__global__ __launch_bounds__(256) void k_cvt(SrcPtrs sp, WsPtrs wp, const int* flagp) {
    int bf = *flagp;
    const void* src = nullptr; ushort_t* dst = nullptr; long n = 0;
    switch (blockIdx.x) {
        case 0:  src = sp.p[3];  dst = wp.wcfg; n = 320;    break;
        case 1:  src = sp.p[4];  dst = wp.bcfg; n = 10;     break;
        case 2:  src = sp.p[5];  dst = wp.eh;   n = 120;    break;
        case 3:  src = sp.p[6];  dst = wp.ew;   n = 24;     break;
        case 4:  src = sp.p[7];  dst = wp.es;   n = 15;     break;
        case 5:  src = sp.p[16]; dst = wp.wis;  n = 65536;  break;
        case 6:  src = sp.p[17]; dst = wp.bis;  n = 256;    break;
        case 8:  src = sp.p[19]; dst = wp.vds;  n = 256;    break;
        case 9:  src = sp.p[20]; dst = wp.bvds; n = 1;      break;
        case 12: src = sp.p[10]; dst = wp.bih;  n = 1024;   break;
        case 13: src = sp.p[11]; dst = wp.bhh;  n = 1024;   break;
        case 14: src = sp.p[21]; dst = wp.wdt;  n = 65536;  break;
        case 15: src = sp.p[22]; dst = wp.bdt;  n = 256;    break;
        case 16: src = sp.p[23]; dst = wp.wd2t; n = 512;    break;
        case 17: src = sp.p[24]; dst = wp.vdt;  n = 256;    break;
        case 18: src = sp.p[25]; dst = wp.bvdt; n = 1;      break;
        case 19: src = sp.p[12]; dst = wp.wihd; n = 1028;   break;
        case 20: src = sp.p[13]; dst = wp.whhd; n = 4;      break;
        case 21: src = sp.p[14]; dst = wp.bihd; n = 4;      break;
        case 22: src = sp.p[15]; dst = wp.bhhd; n = 4;      break;
        default: return;
    }
    for (long i = threadIdx.x; i < n; i += 256) {
        float v = bf ? bs2f(((const ushort_t*)src)[i]) : ((const float*)src)[i];
        dst[i] = f2bs(v);
    }
}

// ---------------------------------------------------------------------------
// k_permA: y=0: Whh (1024x256 row-major) -> fragment-major (encoder layout).
//          y=1: Wih -> PLAIN bf16 copy (row-major; consumed by the AX GEMM).
// ---------------------------------------------------------------------------
__global__ __launch_bounds__(256) void k_permA(
    const void* whh_src, const void* wih_src,
    ushort_t* whhp, ushort_t* wihb, const int* flagp)
{
    int bf = *flagp;
    long base = (long)blockIdx.x * 2048;
    if (blockIdx.y == 1) {
#pragma unroll
        for (int ii = 0; ii < 8; ++ii) {
            long p = base + threadIdx.x + ii * 256;
            wihb[p] = f2bs(gload(wih_src, p, bf));
        }
        return;
    }
#pragma unroll
    for (int ii = 0; ii < 8; ++ii) {
        long p = base + threadIdx.x + ii * 256;
        int c = (int)(p >> 9), l = (int)((p >> 3) & 63), e = (int)(p & 7);
        int w = c >> 5, kk = (c >> 2) & 7, g = c & 3;
        int q = l >> 4, ln = l & 15;
        long si = (long)(g * 256 + w * 16 + ln) * 256 + kk * 32 + q * 8 + e;
        whhp[p] = f2bs(gload(whh_src, si, bf));
    }
}

// ---------------------------------------------------------------------------
// k_permB: Wes (256x512 row-major) -> fragment-major. c = w*16 + kk (kk 0..15).
// ---------------------------------------------------------------------------
__global__ __launch_bounds__(256) void k_permB(
    const void* wes_src, ushort_t* wesp, const int* flagp)
{
    int bf = *flagp;
    long base = (long)blockIdx.x * 2048;
#pragma unroll
    for (int ii = 0; ii < 8; ++ii) {
        long p = base + threadIdx.x + ii * 256;
        int c = (int)(p >> 9), l = (int)((p >> 3) & 63), e = (int)(p & 7);
        int w = c >> 4, kk = c & 15;
        int q = l >> 4, ln = l & 15;
        long si = (long)(w * 16 + ln) * 512 + kk * 32 + q * 8 + e;
        wesp[p] = f2bs(gload(wes_src, si, bf));
    }
}

// ---------------------------------------------------------------------------
// k_build: features. 24576 blocks x 256 thr, 4 rows/block.
// ---------------------------------------------------------------------------
__global__ __launch_bounds__(256) void k_build(
    const void* __restrict__ pq, const void* __restrict__ cfg_in,
    const int* __restrict__ timei, WsPtrs wp, const int* __restrict__ flagp,
    ushort_t* __restrict__ inputs)
{
    int bf = *flagp;
    int ch = threadIdx.x;
    for (int rr = 0; rr < 4; ++rr) {
        long row = (long)blockIdx.x * 4 + rr;
        float v;
        if (ch < 235) {
            v = gload(pq, row * 235 + ch, bf);
        } else if (ch < 245) {
            int j = ch - 235;
            float acc = bs2f(wp.bcfg[j]);
            for (int k = 0; k < 32; ++k)
                acc += gload(cfg_in, row * 32 + k, bf) * bs2f(wp.wcfg[j * 32 + k]);
            v = acc;
        } else if (ch < 250) {
            v = bs2f(wp.eh[timei[row * 3 + 0] * 5 + (ch - 245)]);
        } else if (ch < 253) {
            v = bs2f(wp.ew[timei[row * 3 + 1] * 3 + (ch - 250)]);
        } else {
            v = bs2f(wp.es[timei[row * 3 + 2] * 3 + (ch - 253)]);
        }
        inputs[row * 256 + ch] = f2bs(v);
    }
}

// ---------------------------------------------------------------------------
// k_gemm: out = A @ W.T (+ bias). A:(98304x256), W row-major ws bf16, K=256.
// 128x128 tiles, BK=32, 4 waves of 64x64.
// ---------------------------------------------------------------------------
__global__ __launch_bounds__(256) void k_gemm(
    const ushort_t* __restrict__ A, const ushort_t* __restrict__ W,
    const ushort_t* __restrict__ bias, ushort_t* __restrict__ out,
    int ostride, int gatherB)
{
    const int K = 256;
    __shared__ alignas(16) ushort_t At[128][40];
    __shared__ alignas(16) ushort_t Bt[128][40];

    int tid  = threadIdx.x;
    int lane = tid & 63, wave = tid >> 6;
    int wm = wave >> 1, wn = wave & 1;
    int q = lane >> 4, ln = lane & 15;
    long mbase = (long)blockIdx.x * 128;

    floatx4 acc[4][4];
#pragma unroll
    for (int i = 0; i < 4; ++i)
#pragma unroll
        for (int j = 0; j < 4; ++j) acc[i][j] = (floatx4){0.f, 0.f, 0.f, 0.f};

    for (int k0 = 0; k0 < K; k0 += 32) {
        __syncthreads();
#pragma unroll
        for (int it = 0; it < 2; ++it) {
            int c = tid + it * 256;
            int r = c >> 2, kc = (c & 3) * 8;
            int wrow = gatherB ? (((r & 3) << 8) + ((int)blockIdx.y << 5) + (r >> 2))
                               : ((int)blockIdx.y * 128 + r);
            *reinterpret_cast<short8*>(&At[r][kc]) = ld8(&A[(mbase + r) * K + k0 + kc]);
            *reinterpret_cast<short8*>(&Bt[r][kc]) = ld8(&W[(long)wrow * K + k0 + kc]);
        }
        __syncthreads();
        short8 af[4];
#pragma unroll
        for (int mt = 0; mt < 4; ++mt)
            af[mt] = *reinterpret_cast<const short8*>(&At[wm * 64 + mt * 16 + ln][q * 8]);
#pragma unroll
        for (int nt = 0; nt < 4; ++nt) {
            short8 bf = *reinterpret_cast<const short8*>(&Bt[wn * 64 + nt * 16 + ln][q * 8]);
#pragma unroll
            for (int mt = 0; mt < 4; ++mt)
                acc[mt][nt] = __builtin_amdgcn_mfma_f32_16x16x32_bf16(af[mt], bf, acc[mt][nt], 0, 0, 0);
        }
    }

#pragma unroll
    for (int mt = 0; mt < 4; ++mt)
#pragma unroll
        for (int nt = 0; nt < 4; ++nt)
#pragma unroll
            for (int reg = 0; reg < 4; ++reg) {
                long row = mbase + wm * 64 + mt * 16 + q * 4 + reg;
                int  col = (int)blockIdx.y * 128 + wn * 64 + nt * 16 + ln;
                float bv = bias ? bs2f(bias[col]) : 0.f;
                out[row * (long)ostride + col] = f2bs(acc[mt][nt][reg] + bv);
            }
}

// ---------------------------------------------------------------------------
// k_encoder: 64 blocks x 512 thr (8 waves), 16 batch rows/block.
// Wave w owns cols [w*32, w*32+32) as two 16-col slices s=0,1 (wprime=2w+s).
// Weight stream per wave per step: 96 x 1KB chunks, seq j in [0,96):
//   s=j&1, c=j>>1 ; c<16 -> wes_s chunk c ; else whh_s chunk c-16.
// 12-slot per-wave LDS ring (96KB), slot=j%12 (96%12=0: step-invariant),
// strict vmcnt(11); refills cross barriers and step boundaries.
// One hc fragment read feeds both slices' MFMAs (column-independent).
// Schedule: mid(t-1)|ax/wi|attn j=0..31|epi|barA|gates j=32..95|aval|cell|barC
// ---------------------------------------------------------------------------
#define MFMA16(a, b, c) __builtin_amdgcn_mfma_f32_16x16x32_bf16((a), (b), (c), 0, 0, 0)

DEVFN const ushort_t* sptr2(const ushort_t* const* wesW, const ushort_t* const* whhW,
                            int j) {
    int s = j & 1, c = j >> 1;
    return (c < 16) ? (wesW[s] + (c << 9)) : (whhW[s] + ((c - 16) << 9));
}

__global__ __launch_bounds__(512) void k_encoder(
    const ushort_t* __restrict__ wi, const ushort_t* __restrict__ ax,
    WsPtrs wp, ushort_t* __restrict__ mid)
{
    __shared__ ushort_t wring[8][12][512];             // 96 KB DMA ring
    __shared__ alignas(16) ushort_t hcb[2][16][520];   // 33 KB [h|c] dbuf
    __shared__ alignas(16) float aPartT[16][20];       // [wprime][row]

    int tid  = threadIdx.x;
    int lane = tid & 63, w = tid >> 6;                 // w in [0,8)
    int q = lane >> 4, ln = lane & 15;
    long row0 = (long)blockIdx.x * 16;

    for (int i = tid; i < 2 * 16 * 520; i += 512) ((ushort_t*)hcb)[i] = 0;

    // owned columns: u[0] = w*32+ln, u[1] = u[0]+16
    int u0 = w * 32 + ln;
    float bc[2][4], vds[2];
#pragma unroll
    for (int s = 0; s < 2; ++s) {
        int us = u0 + s * 16;
        bc[s][0] = bs2f(wp.bih[us])       + bs2f(wp.bhh[us]);
        bc[s][1] = bs2f(wp.bih[256 + us]) + bs2f(wp.bhh[256 + us]);
        bc[s][2] = bs2f(wp.bih[512 + us]) + bs2f(wp.bhh[512 + us]);
        bc[s][3] = bs2f(wp.bih[768 + us]) + bs2f(wp.bhh[768 + us]);
        vds[s]   = bs2f(wp.vds[us]);
    }
    float bVd = bs2f(wp.bvds[0]);

    const ushort_t* wesW[2]; const ushort_t* whhW[2];
#pragma unroll
    for (int s = 0; s < 2; ++s) {
        int wprime = 2 * w + s;
        wesW[s] = wp.wes + ((long)wprime << 13) + lane * 8;   // 16 chunks
        whhW[s] = wp.whh + ((long)wprime << 14) + lane * 8;   // 32 chunks
    }

    const ushort_t* wiB[4]; const ushort_t* axB[4];
#pragma unroll
    for (int reg = 0; reg < 4; ++reg) {
        long rw = (row0 + q * 4 + reg) * 96;
        wiB[reg] = wi + rw * 256 + u0;          // +16 for slice 1
        axB[reg] = ax + rw * 1024 + u0 * 4;     // +64 for slice 1
    }
    int mr = tid >> 5, mc = (tid & 31) * 8;            // mid-writer: 16B each
    ushort_t* midB = mid + (row0 + mr) * 96 * 256 + mc;

    float creg[2][4] = {{0.f, 0.f, 0.f, 0.f}, {0.f, 0.f, 0.f, 0.f}};
    __syncthreads();

    // ---- ring prologue: seqs 0..11 in flight
#pragma unroll
    for (int j = 0; j < 12; ++j)
        gload_lds16(sptr2(wesW, whhW, j), &wring[w][j][0]);

    for (int t = 0; t < 96; ++t) {
        ushort_t (*R)[520]  = hcb[t & 1];
        ushort_t (*Wb)[520] = hcb[(t & 1) ^ 1];

        // ---- coalesced mid write for step t-1 (t=0: dummy to slot 95)
        {
            long toff = (long)(t > 0 ? t - 1 : 95) * 256;
            uint4 hv = *reinterpret_cast<const uint4*>(&R[mr][mc]);
            *reinterpret_cast<uint4*>(midB + toff) = hv;
        }
        // ---- ax (2x4x8B) + wi (2x4x2B) prefetch
        short4v axv[2][4]; float wiv[2][4];
#pragma unroll
        for (int reg = 0; reg < 4; ++reg) {
            const ushort_t* a0 = axB[reg] + (long)t * 1024;
            axv[0][reg] = *reinterpret_cast<const short4v*>(a0);
            axv[1][reg] = *reinterpret_cast<const short4v*>(a0 + 64);
            const ushort_t* w0 = wiB[reg] + (long)t * 256;
            wiv[0][reg] = bs2f(w0[0]);
            wiv[1][reg] = bs2f(w0[16]);
        }

        // ---- attn matvec: K=512 over [h|c]; seqs 0..31 (wes, s-interleaved)
        floatx4 acc1[2];
        acc1[0] = (floatx4){0.f, 0.f, 0.f, 0.f};
        acc1[1] = (floatx4){0.f, 0.f, 0.f, 0.f};
#pragma unroll
        for (int kk = 0; kk < 16; ++kk) {
            short8 af = ld8(&R[ln][kk * 32 + q * 8]);
#pragma unroll
            for (int s = 0; s < 2; ++s) {
                const int j = kk * 2 + s;
                VW11();
                short8 bw = ld8(&wring[w][j % 12][lane * 8]);
                acc1[s] = MFMA16(af, bw, acc1[s]);
                gload_lds16(sptr2(wesW, whhW, (j + 12) % 96), &wring[w][j % 12][0]);
            }
        }

        // ---- attn epilogue: tanh, scale, reduce over 16 ln lanes
        float p4[2][4];
#pragma unroll
        for (int s = 0; s < 2; ++s)
#pragma unroll
            for (int reg = 0; reg < 4; ++reg)
                p4[s][reg] = ftanh(acc1[s][reg] + wiv[s][reg]) * vds[s];
#pragma unroll
        for (int m = 1; m < 16; m <<= 1) {
#pragma unroll
            for (int s = 0; s < 2; ++s)
#pragma unroll
                for (int reg = 0; reg < 4; ++reg)
                    p4[s][reg] += __shfl_xor(p4[s][reg], m, 64);
        }
        if (ln == 0) {
#pragma unroll
            for (int s = 0; s < 2; ++s) {
                floatx4 pv = {p4[s][0], p4[s][1], p4[s][2], p4[s][3]};
                *reinterpret_cast<floatx4*>(&aPartT[2 * w + s][q * 4]) = pv;
            }
        }
        bar_lgkm();   // barrier A: aPartT visible (DMA refills stay live)

        // ---- gates: aH = h@Whh.T; seqs 32..95 (whh, s-interleaved)
        floatx4 aH[2][4];
#pragma unroll
        for (int s = 0; s < 2; ++s)
#pragma unroll
            for (int g = 0; g < 4; ++g) aH[s][g] = (floatx4){0.f, 0.f, 0.f, 0.f};
#pragma unroll
        for (int kk = 0; kk < 8; ++kk) {
            short8 af = ld8(&R[ln][kk * 32 + q * 8]);
#pragma unroll
            for (int g = 0; g < 4; ++g) {
#pragma unroll
                for (int s = 0; s < 2; ++s) {
                    const int j = 32 + (kk * 4 + g) * 2 + s;
                    VW11();
                    short8 bw = ld8(&wring[w][j % 12][lane * 8]);
                    aH[s][g] = MFMA16(af, bw, aH[s][g]);
                    gload_lds16(sptr2(wesW, whhW, (j + 12) % 96), &wring[w][j % 12][0]);
                }
            }
        }

        // ---- aval: per-row sum of 16 wprime partials (broadcast b128 reads)
        floatx4 av = {bVd, bVd, bVd, bVd};
#pragma unroll
        for (int ww = 0; ww < 16; ++ww)
            av += *reinterpret_cast<const floatx4*>(&aPartT[ww][q * 4]);

        // ---- cell update: rows q*4+reg, cols u0 and u0+16; write into Wb
#pragma unroll
        for (int s = 0; s < 2; ++s) {
            int us = u0 + s * 16;
#pragma unroll
            for (int reg = 0; reg < 4; ++reg) {
                float a  = av[reg];
                float gi = aH[s][0][reg] + a * bs2f((ushort_t)axv[s][reg][0]) + bc[s][0];
                float gf = aH[s][1][reg] + a * bs2f((ushort_t)axv[s][reg][1]) + bc[s][1];
                float gg = aH[s][2][reg] + a * bs2f((ushort_t)axv[s][reg][2]) + bc[s][2];
                float go = aH[s][3][reg] + a * bs2f((ushort_t)axv[s][reg][3]) + bc[s][3];
                float c2 = sigm(gf) * creg[s][reg] + sigm(gi) * ftanh(gg);
                float h2 = sigm(go) * ftanh(c2);
                creg[s][reg] = c2;
                int r = q * 4 + reg;
                Wb[r][us] = f2bs(h2);
                Wb[r][256 + us] = f2bs(c2);
            }
        }
        bar_lgkm();   // barrier C: new state published
    }

    // drain leftover DMA refills, then the real final mid write (h_96)
    asm volatile("s_waitcnt vmcnt(0)" ::: "memory");
    {
        uint4 hv = *reinterpret_cast<const uint4*>(&hcb[0][mr][mc]);
        *reinterpret_cast<uint4*>(midB + 95L * 256) = hv;
    }
}

// ---------------------------------------------------------------------------
// k_decoder: 1024 blocks (one batch row), 256 thr, 16 sequential steps.
// ---------------------------------------------------------------------------
__global__ __launch_bounds__(256) void k_decoder(
    const ushort_t* __restrict__ mid, const ushort_t* __restrict__ wd,
    WsPtrs wp, const int* __restrict__ flagp, void* __restrict__ out)
{
    __shared__ ushort_t wdl[96][264];
    __shared__ float qL[256], aLs[96], ctxL[256], VdtL[256], gL[4];
    __shared__ float st[3];

    int tid = threadIdx.x;
    long b = blockIdx.x;
    int bf = *flagp;

    for (int c = tid; c < 96 * 256; c += 256) {
        int tp = c >> 8, chn = c & 255;
        wdl[tp][chn] = wd[(b * 96 + tp) * 256 + chn];
    }
    qL[tid] = 0.f; ctxL[tid] = 0.f;
    if (tid < 96) aLs[tid] = 0.f;
    if (tid < 4)  gL[tid] = 0.f;
    VdtL[tid] = bs2f(wp.vdt[tid]);
    if (tid == 0) {
        st[0] = 0.f; st[1] = 0.f;
        st[2] = bs2f(mid[(b * 96 + 95) * 256 + 2]);
    }
    float bVdt = bs2f(wp.bvdt[0]);
    float w2a = bs2f(wp.wd2t[tid * 2]), w2b = bs2f(wp.wd2t[tid * 2 + 1]);
    __syncthreads();

    for (int s = 0; s < 16; ++s) {
        float hi = st[0], ci = st[1], prev = st[2];
        qL[tid] = hi * w2a + ci * w2b;
        __syncthreads();
        {   // attn scores: wave v, lanes split the 256-dot
            int v = tid >> 6, l = tid & 63;
            for (int tp = v; tp < 96; tp += 4) {
                float sacc = 0.f;
#pragma unroll
                for (int e = 0; e < 4; ++e) {
                    int u = l * 4 + e;
                    sacc += ftanh(qL[u] + bs2f(wdl[tp][u])) * VdtL[u];
                }
#pragma unroll
                for (int m = 1; m < 64; m <<= 1) sacc += __shfl_xor(sacc, m, 64);
                if (l == 0) aLs[tp] = sacc + bVdt;
            }
        }
        __syncthreads();
        {
            float acc = 0.f;
            for (int tp = 0; tp < 96; ++tp)
                acc += aLs[tp] * bs2f(mid[(b * 96 + tp) * 256 + tid]);
            ctxL[tid] = acc;
        }
        __syncthreads();
        {   // gates: wave g computes gate g; lanes split the ctx-dot
            int g = tid >> 6, k = tid & 63;
            float part = 0.f;
#pragma unroll
            for (int e = 0; e < 4; ++e) {
                int u = k + e * 64;
                part += bs2f(wp.wihd[g * 257 + u]) * ctxL[u];
            }
#pragma unroll
            for (int m = 1; m < 64; m <<= 1) part += __shfl_xor(part, m, 64);
            if (k == 0)
                gL[g] = part + bs2f(wp.bihd[g]) + bs2f(wp.bhhd[g])
                      + bs2f(wp.whhd[g]) * hi + bs2f(wp.wihd[g * 257 + 256]) * prev;
        }
        __syncthreads();
        if (tid == 0) {
            float c2 = sigm(gL[1]) * ci + sigm(gL[0]) * ftanh(gL[2]);
            float h2 = sigm(gL[3]) * ftanh(c2);
            st[0] = h2; st[1] = c2; st[2] = h2;
            long oi = b * 16 + s;
            if (bf) ((ushort_t*)out)[oi] = f2bs(h2);
            else    ((float*)out)[oi] = h2;
        }
        __syncthreads();
    }
}

// ---------------------------------------------------------------------------
extern "C" void kernel_launch(void* const* d_in, const int* in_sizes, int n_in,
                              void* d_out, int out_size, void* d_ws, size_t ws_size,
                              hipStream_t stream)
{
    const long MT = 1024L * 96;   // 98304 rows

    int* flagp = (int*)d_ws;
    ushort_t* base = (ushort_t*)((char*)d_ws + 256);

    SrcPtrs sp;
    for (int i = 0; i < 26; ++i) sp.p[i] = d_in[i];

    static const long sizes[23] = {
        320, 10, 120, 24, 15, 65536, 256, 131072, 256, 1,
        262144, 262144, 1024, 1024, 65536, 256, 512, 256, 1,
        1028, 4, 4, 4
    };
    ushort_t* ptrs[23];
    long off = 0;
    for (int i = 0; i < 23; ++i) {
        ptrs[i] = base + off;
        off += (sizes[i] + 7) & ~7L;   // 16B-aligned layout
    }

    WsPtrs wp;
    wp.wcfg = ptrs[0];  wp.bcfg = ptrs[1];  wp.eh   = ptrs[2];  wp.ew   = ptrs[3];
    wp.es   = ptrs[4];  wp.wis  = ptrs[5];  wp.bis  = ptrs[6];  wp.wes  = ptrs[7];
    wp.vds  = ptrs[8];  wp.bvds = ptrs[9];  wp.whh  = ptrs[10]; wp.wih  = ptrs[11];
    wp.bih  = ptrs[12]; wp.bhh  = ptrs[13]; wp.wdt  = ptrs[14]; wp.bdt  = ptrs[15];
    wp.wd2t = ptrs[16]; wp.vdt  = ptrs[17]; wp.bvdt = ptrs[18]; wp.wihd = ptrs[19];
    wp.whhd = ptrs[20]; wp.bihd = ptrs[21]; wp.bhhd = ptrs[22];

    ushort_t* inputs = base + off;            // MT*256
    ushort_t* wib    = inputs + MT * 256;     // MT*256
    ushort_t* midb   = wib + MT * 256;        // MT*256
    ushort_t* axb    = midb + MT * 256;       // MT*1024 (201 MB): AX = x@Wih.T
    ushort_t* wdb    = wib;                   // alias: wi dead after encoder

    k_detect<<<1, 64, 0, stream>>>(d_in[3], flagp);
    k_cvt<<<23, 256, 0, stream>>>(sp, wp, flagp);
    k_permA<<<dim3(128, 2), 256, 0, stream>>>(d_in[9], d_in[8], wp.whh, wp.wih, flagp);
    k_permB<<<64, 256, 0, stream>>>(d_in[18], wp.wes, flagp);
    k_build<<<24576, 256, 0, stream>>>(d_in[0], d_in[1], (const int*)d_in[2],
                                       wp, flagp, inputs);
    k_gemm<<<dim3(768, 2), 256, 0, stream>>>(inputs, wp.wis, wp.bis, wib, 256, 0);
    k_gemm<<<dim3(768, 8), 256, 0, stream>>>(inputs, wp.wih, nullptr, axb, 1024, 1);
    k_encoder<<<64, 512, 0, stream>>>(wib, axb, wp, midb);
    k_gemm<<<dim3(768, 2), 256, 0, stream>>>(midb, wp.wdt, wp.bdt, wdb, 256, 0);
    k_decoder<<<1024, 256, 0, stream>>>(midb, wdb, wp, flagp, d_out);
}

// Round 10
// 2287.067 us; speedup vs baseline: 1.5103x; 1.0857x over previous
//
#include <hip/hip_runtime.h>
#include <hip/hip_bf16.h>

// ---------------------------------------------------------------------------
// Round 16: register weight-ring, sized for the 512-thread VGPR budget.
//   R15 proved 512-thr blocks get a >=128 VGPR budget (the 64-curse is a
//   1024-thr artifact) and left the encoder LDS-bound: the weight stream's
//   double pass through LDS (DMA write + ds_read back) is ~1.5MB of the
//   1.75MB/step. This round keeps R15's 8-wave/2-slice structure but streams
//   weights L2 -> VGPR via inline-asm global_load_dwordx4 ("+v" = in-place
//   redefine, ordered after the consuming MFMA), 4-slot ring (32 VGPRs),
//   strict vmcnt(3) + sched_barrier(0x3F7) per consume (rule #18). Slices
//   processed sequentially (acc1[4]/aH[4] reused) to fit ~115 VGPRs.
//   mid/ax/wi stay plain C++ (strict waits safe under any interleave).
//   LDS: hcb 33KB + 60KB pad (1 block/CU, same context as R15's 128 grant).
// ---------------------------------------------------------------------------

typedef unsigned short ushort_t;
using short4v = __attribute__((ext_vector_type(4))) short;   // 4 x bf16
using short8  = __attribute__((ext_vector_type(8))) short;   // 8 x bf16
using floatx4 = __attribute__((ext_vector_type(4))) float;   // MFMA accumulator

#define DEVFN static __device__ __forceinline__

DEVFN float bs2f(ushort_t u) {
    union { float f; unsigned v; } c; c.v = ((unsigned)u) << 16; return c.f;
}
DEVFN ushort_t f2bs(float f) {
    __hip_bfloat16 h = __float2bfloat16(f);
    return *reinterpret_cast<ushort_t*>(&h);
}
DEVFN float gload(const void* p, long i, int bf) {
    if (bf) return bs2f(((const ushort_t*)p)[i]);
    return ((const float*)p)[i];
}
DEVFN float sigm(float x) { return 1.f / (1.f + __expf(-x)); }
DEVFN float ftanh(float x) {
    float t = __expf(-2.f * fabsf(x));
    float r = (1.f - t) / (1.f + t);
    return copysignf(r, x);
}
DEVFN short8 ld8(const ushort_t* p) { return *reinterpret_cast<const short8*>(p); }

// publish LDS writes + barrier WITHOUT draining vmcnt (ring loads stay live)
DEVFN void bar_lgkm() {
    asm volatile("s_waitcnt lgkmcnt(0)" ::: "memory");
    __builtin_amdgcn_s_barrier();
}

// ring refill: in-place register redefine. "+v" ties the new load to the same
// physical regs (no SSA balloon) and orders it after the consuming MFMA.
#define GLD16R(dst, src) \
    asm volatile("global_load_dwordx4 %0, %1, off" : "+v"(dst) : "v"(src))

// strict ring wait: at consume of seq j exactly 3 ring refills are younger;
// foreign plain VMEM only makes the wait stricter (in-order retirement).
// sched_barrier(0x3F7) = everything-but-MFMA may cross: pins the consuming
// MFMA below the wait (rule #18) without constraining DS/VALU scheduling.
#define VW3() do { asm volatile("s_waitcnt vmcnt(3)"); \
                   __builtin_amdgcn_sched_barrier(0x3F7); } while (0)

struct SrcPtrs { const void* p[26]; };
struct WsPtrs {
    // wes/whh hold PERMUTED (fragment-major) data; wih holds PLAIN bf16
    // row-major Wih_e (GEMM input).
    ushort_t *wcfg, *bcfg, *eh, *ew, *es, *wis, *bis, *wes, *vds, *bvds,
             *whh, *wih, *bih, *bhh, *wdt, *bdt, *wd2t, *vdt, *bvdt,
             *wihd, *whhd, *bihd, *bhhd;
};

// ---------------------------------------------------------------------------
__global__ void k_detect(const void* probe, int* flag) {
    if (threadIdx.x == 0 && blockIdx.x == 0) {
        const ushort_t* u = (const ushort_t*)probe;
        int ok = 1;
        for (int i = 0; i < 16; ++i) {
            ushort_t v = u[2 * i];
            int e = (v >> 7) & 0xFF;
            if (!(v == 0 || (e >= 96 && e <= 126))) ok = 0;
        }
        *flag = ok;
    }
}

// ---------------------------------------------------------------------------
// k_cvt: small tensors only (wes/whh/wih are handled by the perm kernels).
// ---------------------------------------------------------------------------
__global__ __launch_bounds__(256) void k_cvt(SrcPtrs sp, WsPtrs wp, const int* flagp) {
    int bf = *flagp;
    const void* src = nullptr; ushort_t* dst = nullptr; long n = 0;
    switch (blockIdx.x) {
        case 0:  src = sp.p[3];  dst = wp.wcfg; n = 320;    break;
        case 1:  src = sp.p[4];  dst = wp.bcfg; n = 10;     break;
        case 2:  src = sp.p[5];  dst = wp.eh;   n = 120;    break;
        case 3:  src = sp.p[6];  dst = wp.ew;   n = 24;     break;
        case 4:  src = sp.p[7];  dst = wp.es;   n = 15;     break;
        case 5:  src = sp.p[16]; dst = wp.wis;  n = 65536;  break;
        case 6:  src = sp.p[17]; dst = wp.bis;  n = 256;    break;
        case 8:  src = sp.p[19]; dst = wp.vds;  n = 256;    break;
        case 9:  src = sp.p[20]; dst = wp.bvds; n = 1;      break;
        case 12: src = sp.p[10]; dst = wp.bih;  n = 1024;   break;
        case 13: src = sp.p[11]; dst = wp.bhh;  n = 1024;   break;
        case 14: src = sp.p[21]; dst = wp.wdt;  n = 65536;  break;
        case 15: src = sp.p[22]; dst = wp.bdt;  n = 256;    break;
        case 16: src = sp.p[23]; dst = wp.wd2t; n = 512;    break;
        case 17: src = sp.p[24]; dst = wp.vdt;  n = 256;    break;
        case 18: src = sp.p[25]; dst = wp.bvdt; n = 1;      break;
        case 19: src = sp.p[12]; dst = wp.wihd; n = 1028;   break;
        case 20: src = sp.p[13]; dst = wp.whhd; n = 4;      break;
        case 21: src = sp.p[14]; dst = wp.bihd; n = 4;      break;
        case 22: src = sp.p[15]; dst = wp.bhhd; n = 4;      break;
        default: return;
    }
    for (long i = threadIdx.x; i < n; i += 256) {
        float v = bf ? bs2f(((const ushort_t*)src)[i]) : ((const float*)src)[i];
        dst[i] = f2bs(v);
    }
}

// ---------------------------------------------------------------------------
// k_permA: y=0: Whh (1024x256 row-major) -> fragment-major (encoder layout).
//          y=1: Wih -> PLAIN bf16 copy (row-major; consumed by the AX GEMM).
// ---------------------------------------------------------------------------
__global__ __launch_bounds__(256) void k_permA(
    const void* whh_src, const void* wih_src,
    ushort_t* whhp, ushort_t* wihb, const int* flagp)
{
    int bf = *flagp;
    long base = (long)blockIdx.x * 2048;
    if (blockIdx.y == 1) {
#pragma unroll
        for (int ii = 0; ii < 8; ++ii) {
            long p = base + threadIdx.x + ii * 256;
            wihb[p] = f2bs(gload(wih_src, p, bf));
        }
        return;
    }
#pragma unroll
    for (int ii = 0; ii < 8; ++ii) {
        long p = base + threadIdx.x + ii * 256;
        int c = (int)(p >> 9), l = (int)((p >> 3) & 63), e = (int)(p & 7);
        int w = c >> 5, kk = (c >> 2) & 7, g = c & 3;
        int q = l >> 4, ln = l & 15;
        long si = (long)(g * 256 + w * 16 + ln) * 256 + kk * 32 + q * 8 + e;
        whhp[p] = f2bs(gload(whh_src, si, bf));
    }
}

// ---------------------------------------------------------------------------
// k_permB: Wes (256x512 row-major) -> fragment-major. c = w*16 + kk (kk 0..15).
// ---------------------------------------------------------------------------
__global__ __launch_bounds__(256) void k_permB(
    const void* wes_src, ushort_t* wesp, const int* flagp)
{
    int bf = *flagp;
    long base = (long)blockIdx.x * 2048;
#pragma unroll
    for (int ii = 0; ii < 8; ++ii) {
        long p = base + threadIdx.x + ii * 256;
        int c = (int)(p >> 9), l = (int)((p >> 3) & 63), e = (int)(p & 7);
        int w = c >> 4, kk = c & 15;
        int q = l >> 4, ln = l & 15;
        long si = (long)(w * 16 + ln) * 512 + kk * 32 + q * 8 + e;
        wesp[p] = f2bs(gload(wes_src, si, bf));
    }
}

// ---------------------------------------------------------------------------
// k_build: features. 24576 blocks x 256 thr, 4 rows/block.
// ---------------------------------------------------------------------------
__global__ __launch_bounds__(256) void k_build(
    const void* __restrict__ pq, const void* __restrict__ cfg_in,
    const int* __restrict__ timei, WsPtrs wp, const int* __restrict__ flagp,
    ushort_t* __restrict__ inputs)
{
    int bf = *flagp;
    int ch = threadIdx.x;
    for (int rr = 0; rr < 4; ++rr) {
        long row = (long)blockIdx.x * 4 + rr;
        float v;
        if (ch < 235) {
            v = gload(pq, row * 235 + ch, bf);
        } else if (ch < 245) {
            int j = ch - 235;
            float acc = bs2f(wp.bcfg[j]);
            for (int k = 0; k < 32; ++k)
                acc += gload(cfg_in, row * 32 + k, bf) * bs2f(wp.wcfg[j * 32 + k]);
            v = acc;
        } else if (ch < 250) {
            v = bs2f(wp.eh[timei[row * 3 + 0] * 5 + (ch - 245)]);
        } else if (ch < 253) {
            v = bs2f(wp.ew[timei[row * 3 + 1] * 3 + (ch - 250)]);
        } else {
            v = bs2f(wp.es[timei[row * 3 + 2] * 3 + (ch - 253)]);
        }
        inputs[row * 256 + ch] = f2bs(v);
    }
}

// ---------------------------------------------------------------------------
// k_gemm: out = A @ W.T (+ bias). A:(98304x256), W row-major ws bf16, K=256.
// 128x128 tiles, BK=32, 4 waves of 64x64.
// ---------------------------------------------------------------------------
__global__ __launch_bounds__(256) void k_gemm(
    const ushort_t* __restrict__ A, const ushort_t* __restrict__ W,
    const ushort_t* __restrict__ bias, ushort_t* __restrict__ out,
    int ostride, int gatherB)
{
    const int K = 256;
    __shared__ alignas(16) ushort_t At[128][40];
    __shared__ alignas(16) ushort_t Bt[128][40];

    int tid  = threadIdx.x;
    int lane = tid & 63, wave = tid >> 6;
    int wm = wave >> 1, wn = wave & 1;
    int q = lane >> 4, ln = lane & 15;
    long mbase = (long)blockIdx.x * 128;

    floatx4 acc[4][4];
#pragma unroll
    for (int i = 0; i < 4; ++i)
#pragma unroll
        for (int j = 0; j < 4; ++j) acc[i][j] = (floatx4){0.f, 0.f, 0.f, 0.f};

    for (int k0 = 0; k0 < K; k0 += 32) {
        __syncthreads();
#pragma unroll
        for (int it = 0; it < 2; ++it) {
            int c = tid + it * 256;
            int r = c >> 2, kc = (c & 3) * 8;
            int wrow = gatherB ? (((r & 3) << 8) + ((int)blockIdx.y << 5) + (r >> 2))
                               : ((int)blockIdx.y * 128 + r);
            *reinterpret_cast<short8*>(&At[r][kc]) = ld8(&A[(mbase + r) * K + k0 + kc]);
            *reinterpret_cast<short8*>(&Bt[r][kc]) = ld8(&W[(long)wrow * K + k0 + kc]);
        }
        __syncthreads();
        short8 af[4];
#pragma unroll
        for (int mt = 0; mt < 4; ++mt)
            af[mt] = *reinterpret_cast<const short8*>(&At[wm * 64 + mt * 16 + ln][q * 8]);
#pragma unroll
        for (int nt = 0; nt < 4; ++nt) {
            short8 bf = *reinterpret_cast<const short8*>(&Bt[wn * 64 + nt * 16 + ln][q * 8]);
#pragma unroll
            for (int mt = 0; mt < 4; ++mt)
                acc[mt][nt] = __builtin_amdgcn_mfma_f32_16x16x32_bf16(af[mt], bf, acc[mt][nt], 0, 0, 0);
        }
    }

#pragma unroll
    for (int mt = 0; mt < 4; ++mt)
#pragma unroll
        for (int nt = 0; nt < 4; ++nt)
#pragma unroll
            for (int reg = 0; reg < 4; ++reg) {
                long row = mbase + wm * 64 + mt * 16 + q * 4 + reg;
                int  col = (int)blockIdx.y * 128 + wn * 64 + nt * 16 + ln;
                float bv = bias ? bs2f(bias[col]) : 0.f;
                out[row * (long)ostride + col] = f2bs(acc[mt][nt][reg] + bv);
            }
}

// ---------------------------------------------------------------------------
// k_encoder: 64 blocks x 512 thr (8 waves), 16 rows/block, 1 block/CU.
// Wave w owns cols [w*32, w*32+32) as two 16-col slices s=0,1 (wprime=2w+s).
// Weight stream per wave per step: 96 x 1KB chunks, seq j in [0,96):
//   j<32: wes[j>>4] chunk (j&15) ; j>=32: whh[(j-32)>>5] chunk ((j-32)&31).
// 4-slot REGISTER ring Wr[4] (32 VGPRs), slot = j&3 (96%4==0: invariant),
// refilled by asm global_load_dwordx4 ("+v"), strict vmcnt(3)+sched_barrier;
// refills cross barriers and the step boundary. Slices sequential so
// acc1[4]/aH[4] are reused (fits the 128-VGPR budget R15 proved).
// Schedule: mid(t-1)|ax/wi| attn s0,s1 (seqs 0..31)+epi | barA |
//           aval | gates+cell s0 (32..63), s1 (64..95) | barC
// ---------------------------------------------------------------------------
#define MFMA16(a, b, c) __builtin_amdgcn_mfma_f32_16x16x32_bf16((a), (b), (c), 0, 0, 0)

__global__ __launch_bounds__(512) void k_encoder(
    const ushort_t* __restrict__ wi, const ushort_t* __restrict__ ax,
    WsPtrs wp, ushort_t* __restrict__ mid)
{
    __shared__ alignas(16) ushort_t hcb[2][16][520];   // 33 KB [h|c] dbuf
    __shared__ alignas(16) float aPartT[16][20];       // [wprime][row]
    __shared__ ushort_t occupancy_pad[30720];          // 60 KB: 1 block/CU

    int tid  = threadIdx.x;
    int lane = tid & 63, w = tid >> 6;                 // w in [0,8)
    int q = lane >> 4, ln = lane & 15;
    long row0 = (long)blockIdx.x * 16;
    int u0 = w * 32 + ln;

    for (int i = tid; i < 2 * 16 * 520; i += 512) ((ushort_t*)hcb)[i] = 0;

    float bc[2][4], vds[2];
#pragma unroll
    for (int s = 0; s < 2; ++s) {
        int us = u0 + s * 16;
        bc[s][0] = bs2f(wp.bih[us])       + bs2f(wp.bhh[us]);
        bc[s][1] = bs2f(wp.bih[256 + us]) + bs2f(wp.bhh[256 + us]);
        bc[s][2] = bs2f(wp.bih[512 + us]) + bs2f(wp.bhh[512 + us]);
        bc[s][3] = bs2f(wp.bih[768 + us]) + bs2f(wp.bhh[768 + us]);
        vds[s]   = bs2f(wp.vds[us]);
    }
    float bVd = bs2f(wp.bvds[0]);

    const ushort_t* wesW0 = wp.wes + ((long)(2 * w)     << 13) + lane * 8;
    const ushort_t* wesW1 = wp.wes + ((long)(2 * w + 1) << 13) + lane * 8;
    const ushort_t* whhW0 = wp.whh + ((long)(2 * w)     << 14) + lane * 8;
    const ushort_t* whhW1 = wp.whh + ((long)(2 * w + 1) << 14) + lane * 8;

    // single base pointers (per-reg offsets recomputed; saves ~12 VGPRs)
    const ushort_t* wiB0 = wi + ((row0 + q * 4) * 96) * 256 + u0;
    const ushort_t* axB0 = ax + ((row0 + q * 4) * 96) * 1024 + u0 * 4;

    int mr = tid >> 5, mc = (tid & 31) * 8;            // mid-writer: 16B each
    ushort_t* midB = mid + (row0 + mr) * 96 * 256 + mc;

    // keep the pad alive (branch never taken: gridDim.x == 64)
    if (blockIdx.x > 60000) {
        occupancy_pad[tid] = (ushort_t)tid;
        midB[0] = occupancy_pad[(tid + 1) & 511];
    }

    float creg[2][4] = {{0.f, 0.f, 0.f, 0.f}, {0.f, 0.f, 0.f, 0.f}};
    __syncthreads();

    // seq j -> global chunk address (compile-time resolved: j is unrolled)
    auto sp3 = [&](int j) -> const ushort_t* {
        if (j < 16)  return wesW0 + ((j & 15) << 9);
        if (j < 32)  return wesW1 + ((j & 15) << 9);
        if (j < 64)  return whhW0 + (((j - 32) & 31) << 9);
        return whhW1 + (((j - 64) & 31) << 9);
    };

    // ---- ring prologue: seqs 0..3 in flight
    short8 Wr[4] = {};
#pragma unroll
    for (int j = 0; j < 4; ++j) GLD16R(Wr[j], sp3(j));

    for (int t = 0; t < 96; ++t) {
        ushort_t (*R)[520]  = hcb[t & 1];
        ushort_t (*Wb)[520] = hcb[(t & 1) ^ 1];

        // ---- coalesced mid write for step t-1 (t=0: dummy to slot 95)
        {
            long toff = (long)(t > 0 ? t - 1 : 95) * 256;
            uint4 hv = *reinterpret_cast<const uint4*>(&R[mr][mc]);
            *reinterpret_cast<uint4*>(midB + toff) = hv;
        }
        // ---- ax (2x4x8B) + wi (2x4x2B) prefetch (plain; compiler-scheduled)
        short4v axv[2][4]; float wiv[2][4];
#pragma unroll
        for (int reg = 0; reg < 4; ++reg) {
            const ushort_t* a0 = axB0 + ((long)reg * 96 + t) * 1024;
            axv[0][reg] = *reinterpret_cast<const short4v*>(a0);
            axv[1][reg] = *reinterpret_cast<const short4v*>(a0 + 64);
            const ushort_t* w0 = wiB0 + ((long)reg * 96 + t) * 256;
            wiv[0][reg] = bs2f(w0[0]);
            wiv[1][reg] = bs2f(w0[16]);
        }

        // ---- attn matvec per slice: K=512 over [h|c]; seqs s*16 .. s*16+15
#pragma unroll
        for (int s = 0; s < 2; ++s) {
            floatx4 acc1 = (floatx4){0.f, 0.f, 0.f, 0.f};
#pragma unroll
            for (int c = 0; c < 16; ++c) {
                const int j = s * 16 + c;
                short8 af = ld8(&R[ln][c * 32 + q * 8]);
                VW3();
                acc1 = MFMA16(af, Wr[j & 3], acc1);
                GLD16R(Wr[j & 3], sp3((j + 4) % 96));
            }
            // epilogue: tanh, scale, reduce over 16 ln lanes
            float p4[4];
#pragma unroll
            for (int reg = 0; reg < 4; ++reg)
                p4[reg] = ftanh(acc1[reg] + wiv[s][reg]) * vds[s];
#pragma unroll
            for (int m = 1; m < 16; m <<= 1) {
#pragma unroll
                for (int reg = 0; reg < 4; ++reg)
                    p4[reg] += __shfl_xor(p4[reg], m, 64);
            }
            if (ln == 0) {
                floatx4 pv = {p4[0], p4[1], p4[2], p4[3]};
                *reinterpret_cast<floatx4*>(&aPartT[2 * w + s][q * 4]) = pv;
            }
        }
        bar_lgkm();   // barrier A: aPartT visible (ring loads stay live)

        // ---- aval: per-row sum of 16 wprime partials (broadcast b128 reads)
        floatx4 av = {bVd, bVd, bVd, bVd};
#pragma unroll
        for (int ww = 0; ww < 16; ++ww)
            av += *reinterpret_cast<const floatx4*>(&aPartT[ww][q * 4]);

        // ---- gates + cell per slice: seqs 32+s*32 .. 32+s*32+31
#pragma unroll
        for (int s = 0; s < 2; ++s) {
            floatx4 aH[4];
#pragma unroll
            for (int g = 0; g < 4; ++g) aH[g] = (floatx4){0.f, 0.f, 0.f, 0.f};
#pragma unroll
            for (int kk = 0; kk < 8; ++kk) {
                short8 af = ld8(&R[ln][kk * 32 + q * 8]);
#pragma unroll
                for (int g = 0; g < 4; ++g) {
                    const int j = 32 + s * 32 + kk * 4 + g;
                    VW3();
                    aH[g] = MFMA16(af, Wr[j & 3], aH[g]);
                    GLD16R(Wr[j & 3], sp3((j + 4) % 96));   // wraps to next step
                }
            }
            int us = u0 + s * 16;
#pragma unroll
            for (int reg = 0; reg < 4; ++reg) {
                float a  = av[reg];
                float gi = aH[0][reg] + a * bs2f((ushort_t)axv[s][reg][0]) + bc[s][0];
                float gf = aH[1][reg] + a * bs2f((ushort_t)axv[s][reg][1]) + bc[s][1];
                float gg = aH[2][reg] + a * bs2f((ushort_t)axv[s][reg][2]) + bc[s][2];
                float go = aH[3][reg] + a * bs2f((ushort_t)axv[s][reg][3]) + bc[s][3];
                float c2 = sigm(gf) * creg[s][reg] + sigm(gi) * ftanh(gg);
                float h2 = sigm(go) * ftanh(c2);
                creg[s][reg] = c2;
                int r = q * 4 + reg;
                Wb[r][us] = f2bs(h2);
                Wb[r][256 + us] = f2bs(c2);
            }
        }
        bar_lgkm();   // barrier C: new state published
    }

    // retire dangling ring loads, then the real final mid write (h_96)
    asm volatile("s_waitcnt vmcnt(0)" ::: "memory");
    {
        uint4 hv = *reinterpret_cast<const uint4*>(&hcb[0][mr][mc]);
        *reinterpret_cast<uint4*>(midB + 95L * 256) = hv;
    }
}

// ---------------------------------------------------------------------------
// k_decoder: 1024 blocks (one batch row), 256 thr, 16 sequential steps.
// ---------------------------------------------------------------------------
__global__ __launch_bounds__(256) void k_decoder(
    const ushort_t* __restrict__ mid, const ushort_t* __restrict__ wd,
    WsPtrs wp, const int* __restrict__ flagp, void* __restrict__ out)
{
    __shared__ ushort_t wdl[96][264];
    __shared__ float qL[256], aLs[96], ctxL[256], VdtL[256], gL[4];
    __shared__ float st[3];

    int tid = threadIdx.x;
    long b = blockIdx.x;
    int bf = *flagp;

    for (int c = tid; c < 96 * 256; c += 256) {
        int tp = c >> 8, chn = c & 255;
        wdl[tp][chn] = wd[(b * 96 + tp) * 256 + chn];
    }
    qL[tid] = 0.f; ctxL[tid] = 0.f;
    if (tid < 96) aLs[tid] = 0.f;
    if (tid < 4)  gL[tid] = 0.f;
    VdtL[tid] = bs2f(wp.vdt[tid]);
    if (tid == 0) {
        st[0] = 0.f; st[1] = 0.f;
        st[2] = bs2f(mid[(b * 96 + 95) * 256 + 2]);
    }
    float bVdt = bs2f(wp.bvdt[0]);
    float w2a = bs2f(wp.wd2t[tid * 2]), w2b = bs2f(wp.wd2t[tid * 2 + 1]);
    __syncthreads();

    for (int s = 0; s < 16; ++s) {
        float hi = st[0], ci = st[1], prev = st[2];
        qL[tid] = hi * w2a + ci * w2b;
        __syncthreads();
        {   // attn scores: wave v, lanes split the 256-dot
            int v = tid >> 6, l = tid & 63;
            for (int tp = v; tp < 96; tp += 4) {
                float sacc = 0.f;
#pragma unroll
                for (int e = 0; e < 4; ++e) {
                    int u = l * 4 + e;
                    sacc += ftanh(qL[u] + bs2f(wdl[tp][u])) * VdtL[u];
                }
#pragma unroll
                for (int m = 1; m < 64; m <<= 1) sacc += __shfl_xor(sacc, m, 64);
                if (l == 0) aLs[tp] = sacc + bVdt;
            }
        }
        __syncthreads();
        {
            float acc = 0.f;
            for (int tp = 0; tp < 96; ++tp)
                acc += aLs[tp] * bs2f(mid[(b * 96 + tp) * 256 + tid]);
            ctxL[tid] = acc;
        }
        __syncthreads();
        {   // gates: wave g computes gate g; lanes split the ctx-dot
            int g = tid >> 6, k = tid & 63;
            float part = 0.f;
#pragma unroll
            for (int e = 0; e < 4; ++e) {
                int u = k + e * 64;
                part += bs2f(wp.wihd[g * 257 + u]) * ctxL[u];
            }
#pragma unroll
            for (int m = 1; m < 64; m <<= 1) part += __shfl_xor(part, m, 64);
            if (k == 0)
                gL[g] = part + bs2f(wp.bihd[g]) + bs2f(wp.bhhd[g])
                      + bs2f(wp.whhd[g]) * hi + bs2f(wp.wihd[g * 257 + 256]) * prev;
        }
        __syncthreads();
        if (tid == 0) {
            float c2 = sigm(gL[1]) * ci + sigm(gL[0]) * ftanh(gL[2]);
            float h2 = sigm(gL[3]) * ftanh(c2);
            st[0] = h2; st[1] = c2; st[2] = h2;
            long oi = b * 16 + s;
            if (bf) ((ushort_t*)out)[oi] = f2bs(h2);
            else    ((float*)out)[oi] = h2;
        }
        __syncthreads();
    }
}

// ---------------------------------------------------------------------------
extern "C" void kernel_launch(void* const* d_in, const int* in_sizes, int n_in,
                              void* d_out, int out_size, void* d_ws, size_t ws_size,
                              hipStream_t stream)
{
    const long MT = 1024L * 96;   // 98304 rows

    int* flagp = (int*)d_ws;
    ushort_t* base = (ushort_t*)((char*)d_ws + 256);

    SrcPtrs sp;
    for (int i = 0; i < 26; ++i) sp.p[i] = d_in[i];

    static const long sizes[23] = {
        320, 10, 120, 24, 15, 65536, 256, 131072, 256, 1,
        262144, 262144, 1024, 1024, 65536, 256, 512, 256, 1,
        1028, 4, 4, 4
    };
    ushort_t* ptrs[23];
    long off = 0;
    for (int i = 0; i < 23; ++i) {
        ptrs[i] = base + off;
        off += (sizes[i] + 7) & ~7L;   // 16B-aligned layout
    }

    WsPtrs wp;
    wp.wcfg = ptrs[0];  wp.bcfg = ptrs[1];  wp.eh   = ptrs[2];  wp.ew   = ptrs[3];
    wp.es   = ptrs[4];  wp.wis  = ptrs[5];  wp.bis  = ptrs[6];  wp.wes  = ptrs[7];
    wp.vds  = ptrs[8];  wp.bvds = ptrs[9];  wp.whh  = ptrs[10]; wp.wih  = ptrs[11];
    wp.bih  = ptrs[12]; wp.bhh  = ptrs[13]; wp.wdt  = ptrs[14]; wp.bdt  = ptrs[15];
    wp.wd2t = ptrs[16]; wp.vdt  = ptrs[17]; wp.bvdt = ptrs[18]; wp.wihd = ptrs[19];
    wp.whhd = ptrs[20]; wp.bihd = ptrs[21]; wp.bhhd = ptrs[22];

    ushort_t* inputs = base + off;            // MT*256
    ushort_t* wib    = inputs + MT * 256;     // MT*256
    ushort_t* midb   = wib + MT * 256;        // MT*256
    ushort_t* axb    = midb + MT * 256;       // MT*1024 (201 MB): AX = x@Wih.T
    ushort_t* wdb    = wib;                   // alias: wi dead after encoder

    k_detect<<<1, 64, 0, stream>>>(d_in[3], flagp);
    k_cvt<<<23, 256, 0, stream>>>(sp, wp, flagp);
    k_permA<<<dim3(128, 2), 256, 0, stream>>>(d_in[9], d_in[8], wp.whh, wp.wih, flagp);
    k_permB<<<64, 256, 0, stream>>>(d_in[18], wp.wes, flagp);
    k_build<<<24576, 256, 0, stream>>>(d_in[0], d_in[1], (const int*)d_in[2],
                                       wp, flagp, inputs);
    k_gemm<<<dim3(768, 2), 256, 0, stream>>>(inputs, wp.wis, wp.bis, wib, 256, 0);
    k_gemm<<<dim3(768, 8), 256, 0, stream>>>(inputs, wp.wih, nullptr, axb, 1024, 1);
    k_encoder<<<64, 512, 0, stream>>>(wib, axb, wp, midb);
    k_gemm<<<dim3(768, 2), 256, 0, stream>>>(midb, wp.wdt, wp.bdt, wdb, 256, 0);
    k_decoder<<<1024, 256, 0, stream>>>(midb, wdb, wp, flagp, d_out);
}